// Round 10
// baseline (285.409 us; speedup 1.0000x reference)
//
#include <hip/hip_runtime.h>
#include <hip/hip_bf16.h>

// Problem constants (reference: B=8, L=1024, C=4, D=64, H=8, NB=2, K=16)
#define BB   8
#define LL   1024
#define DD   64
#define D2   128
#define D4   256
#define HH   8
#define DH   16

typedef __attribute__((ext_vector_type(8))) short short8;   // 8 bf16 (4 VGPRs)
typedef __attribute__((ext_vector_type(4))) float floatx4;  // MFMA C/D

#define LOG2E 1.4426950408889634f

// bf16 split-weight arena offsets (elements)
#define OFF_WIN1   0        // [256][128] hi, lo at +32768
#define OFF_WIN2   65536    // [64][256]  hi, lo at +16384
#define OFF_LAY0   98304
#define LAY_STRIDE 131072
#define OFF_WQ     0        // [128][64] hi, lo +8192
#define OFF_WK     16384
#define OFF_WV     32768
#define OFF_WO     49152    // [64][128] hi, lo +8192
#define OFF_W1     65536    // [256][64] hi, lo +16384
#define OFF_W2     98304    // [64][256] hi, lo +16384
#define OFF_WH1    360448   // [256][64] hi, lo +16384
#define OFF_WH2    393216   // [64][256] hi, lo +16384

__device__ __forceinline__ float gelu_tanh(float u) {
  float t = tanhf(0.7978845608028654f * (u + 0.044715f * u * u * u));
  return 0.5f * u * (1.0f + t);
}

__device__ __forceinline__ float wave_reduce_sum(float v) {
#pragma unroll
  for (int m = 32; m >= 1; m >>= 1) v += __shfl_xor(v, m, 64);
  return v;
}

__device__ __forceinline__ unsigned short f2bf(float x) {  // RNE
  unsigned u = __float_as_uint(x);
  u += 0x7fffu + ((u >> 16) & 1u);
  return (unsigned short)(u >> 16);
}

__device__ __forceinline__ float bf2f(unsigned short x) {
  return __uint_as_float(((unsigned)x) << 16);
}

__device__ __forceinline__ void split_bf(float v, unsigned short& hi,
                                         unsigned short& lo) {
  hi = f2bf(v);
  lo = f2bf(v - bf2f(hi));
}

// 16x16 output tile over K with 3-term bf16 split.
// Three INDEPENDENT accumulators (3x MFMA ILP on the dependency chain),
// summed at the end.
template <int K, int KP>
__device__ __forceinline__ floatx4 mfma_tile(
    const unsigned short* Ah, const unsigned short* Al,
    const unsigned short* __restrict__ Bh, const unsigned short* __restrict__ Bl,
    int lq, int quad, floatx4 C) {
  floatx4 C1 = {0.0f, 0.0f, 0.0f, 0.0f};
  floatx4 C2 = {0.0f, 0.0f, 0.0f, 0.0f};
#pragma unroll
  for (int kk = 0; kk < K; kk += 32) {
    short8 ah = *(const short8*)(Ah + lq * KP + kk + quad * 8);
    short8 al = *(const short8*)(Al + lq * KP + kk + quad * 8);
    short8 bh = *(const short8*)(Bh + lq * K + kk + quad * 8);
    short8 bl = *(const short8*)(Bl + lq * K + kk + quad * 8);
    C  = __builtin_amdgcn_mfma_f32_16x16x32_bf16(ah, bh, C, 0, 0, 0);
    C1 = __builtin_amdgcn_mfma_f32_16x16x32_bf16(al, bh, C1, 0, 0, 0);
    C2 = __builtin_amdgcn_mfma_f32_16x16x32_bf16(ah, bl, C2, 0, 0, 0);
  }
#pragma unroll
  for (int r = 0; r < 4; ++r) C[r] += C1[r] + C2[r];
  return C;
}

// ---------------------------------------------------------------------------
// K0: merged weight prep (bid<2048) + RBF bias (rest). Flat grid.
// bias stored PRE-SCALED by log2(e) so attn softmax runs in exp2 domain.
// ---------------------------------------------------------------------------
struct PrepArgs {
  const float* src[16];
  int Kd[16], Nd[16], dst[16], elems[16];
};

__global__ __launch_bounds__(256) void k_prep_bias(
    PrepArgs a, unsigned short* __restrict__ arena,
    const float* __restrict__ s, const float* __restrict__ rbf_c,
    const float* __restrict__ rbf_logw, const float* __restrict__ rbf_w,
    const float* __restrict__ rbf_b, unsigned short* __restrict__ biasT) {
  int bid = blockIdx.x, t = threadIdx.x;
  if (bid < 2048) {
    int mid = bid >> 7;
    int e = (bid & 127) * 256 + t;
    int KN = a.elems[mid];
    if (e >= KN) return;
    int K = a.Kd[mid], N = a.Nd[mid];
    int n = e / K, k = e - n * K;
    float wv = a.src[mid][k * N + n];
    unsigned short hi, lo;
    split_bf(wv, hi, lo);
    arena[a.dst[mid] + e] = hi;
    arena[a.dst[mid] + KN + e] = lo;
    return;
  }
  int rem = bid - 2048;
  int lay = rem >> 12;
  int id = (rem & 4095) * 256 + t;
  int q = id >> 10, k = id & 1023;
  float dd = s[q] - s[k];  // dist[q,k] = s[q]-s[k]
  float acc[8];
#pragma unroll
  for (int h = 0; h < 8; ++h) acc[h] = rbf_b[lay * 8 + h];
#pragma unroll 1
  for (int f = 0; f < 16; ++f) {
    float c = rbf_c[lay * 16 + f];
    float inv2w2 = 0.5f * __expf(-2.0f * rbf_logw[lay * 16 + f]);
    float e = dd - c;
    float ph = __expf(-e * e * inv2w2);
#pragma unroll
    for (int h = 0; h < 8; ++h)
      acc[h] = fmaf(ph, rbf_w[lay * 128 + f * 8 + h], acc[h]);
  }
  unsigned short* bT = biasT + (size_t)lay * 8 * 1024 * 1024;
#pragma unroll
  for (int h = 0; h < 8; ++h)
    bT[(size_t)(h * 1024 + q) * 1024 + k] = f2bf(acc[h] * LOG2E);
}

// Shared QKV tail: LN(xl) -> split -> 3 MFMA mats -> q/k global, v transposed.
__device__ __forceinline__ void qkv_tail(
    const float* xl, unsigned short* Sh, unsigned short* Sl,
    const unsigned short* __restrict__ arena, int lay,
    const float* __restrict__ ln_s, const float* __restrict__ ln_b,
    const float* __restrict__ bq, const float* __restrict__ bk,
    const float* __restrict__ bv, unsigned short* __restrict__ qo,
    unsigned short* __restrict__ ko, unsigned short* __restrict__ voT,
    int tok0, int t) {
  int w = t >> 6, lane = t & 63;
  int lq = lane & 15, quad = lane >> 4;
  float ss = ln_s[lay * 64 + lane], sb = ln_b[lay * 64 + lane];
#pragma unroll
  for (int tk = 0; tk < 4; ++tk) {
    int tok = w * 4 + tk;
    float v = xl[tok * 64 + lane];
    float mean = wave_reduce_sum(v) * 0.015625f;
    float d = v - mean;
    float var = wave_reduce_sum(d * d) * 0.015625f;
    float hv = d * rsqrtf(var + 1e-6f) * ss + sb;
    unsigned short hi, lo;
    split_bf(hv, hi, lo);
    Sh[tok * 72 + lane] = hi;
    Sl[tok * 72 + lane] = lo;
  }
  __syncthreads();
  int b = tok0 >> 10, l0 = tok0 & 1023;
#pragma unroll 1
  for (int mat = 0; mat < 3; ++mat) {
    const unsigned short* Bh =
        arena + OFF_LAY0 + lay * LAY_STRIDE + mat * 16384;
    const unsigned short* Bl = Bh + 8192;
    const float* bias = (mat == 0 ? bq : mat == 1 ? bk : bv) + lay * 128;
#pragma unroll
    for (int j = 0; j < 2; ++j) {
      int tl = w + j * 4;  // head index
      int n = tl * 16 + lq;
      float bb = bias[n];
      floatx4 C = {bb, bb, bb, bb};
      C = mfma_tile<64, 72>(Sh, Sl, Bh + tl * 16 * 64, Bl + tl * 16 * 64,
                            lq, quad, C);
      if (mat < 2) {
        unsigned short* outp = (mat == 0 ? qo : ko);
        size_t basea = ((size_t)(b * 8 + tl) * 1024 + l0 + quad * 4) * 16 + lq;
#pragma unroll
        for (int r = 0; r < 4; ++r)
          outp[basea + (size_t)r * 16] = f2bf(C[r]);
      } else {
        size_t basev = ((size_t)(b * 8 + tl) * 16 + lq) * 1024 + l0 + quad * 4;
#pragma unroll
        for (int r = 0; r < 4; ++r)
          voT[basev + r] = f2bf(C[r]);
      }
    }
  }
}

// ---------------------------------------------------------------------------
// K1: input MLP + LN1 + QKV (layer 0). 16 tokens/block.
// ---------------------------------------------------------------------------
__global__ __launch_bounds__(256) void k_in_qkv(
    const float* __restrict__ embed, const float* __restrict__ z,
    const float* __restrict__ cond, const unsigned short* __restrict__ arena,
    const float* __restrict__ bin1, const float* __restrict__ bin2,
    float* __restrict__ x, const float* __restrict__ ln1_s,
    const float* __restrict__ ln1_b, const float* __restrict__ bq,
    const float* __restrict__ bk, const float* __restrict__ bv,
    unsigned short* __restrict__ qo, unsigned short* __restrict__ ko,
    unsigned short* __restrict__ voT) {
  __shared__ __align__(16) unsigned short Ah[16 * 136], Al[16 * 136];
  __shared__ __align__(16) unsigned short Hh[16 * 264], Hl[16 * 264];
  __shared__ __align__(16) unsigned short Sh[16 * 72], Sl[16 * 72];
  __shared__ float xl[16 * 64];
  int t = threadIdx.x, w = t >> 6, lane = t & 63;
  int lq = lane & 15, quad = lane >> 4;
  int tok0 = blockIdx.x * 16;
  for (int idx = t; idx < 2048; idx += 256) {
    int tok = idx >> 7, dim = idx & 127;
    int bl = tok0 + tok, l = bl & (LL - 1);
    float v;
    if (dim < 123) v = embed[l * 123 + dim];
    else if (dim == 123) v = z[bl];
    else v = cond[dim - 124];
    unsigned short hi, lo;
    split_bf(v, hi, lo);
    Ah[tok * 136 + dim] = hi;
    Al[tok * 136 + dim] = lo;
  }
  __syncthreads();
  // G1: 128 -> 256, gelu
  const unsigned short* B1h = arena + OFF_WIN1;
  const unsigned short* B1l = B1h + 32768;
#pragma unroll
  for (int j = 0; j < 4; ++j) {
    int tl = w * 4 + j, n = tl * 16 + lq;
    float bb = bin1[n];
    floatx4 C = {bb, bb, bb, bb};
    C = mfma_tile<128, 136>(Ah, Al, B1h + tl * 16 * 128, B1l + tl * 16 * 128,
                            lq, quad, C);
#pragma unroll
    for (int r = 0; r < 4; ++r) {
      float g = gelu_tanh(C[r]);
      unsigned short hi, lo;
      split_bf(g, hi, lo);
      Hh[(quad * 4 + r) * 264 + n] = hi;
      Hl[(quad * 4 + r) * 264 + n] = lo;
    }
  }
  __syncthreads();
  // G2: 256 -> 64 -> x (global + xl)
  const unsigned short* B2h = arena + OFF_WIN2;
  const unsigned short* B2l = B2h + 16384;
  {
    int n = w * 16 + lq;
    float bb = bin2[n];
    floatx4 C = {bb, bb, bb, bb};
    C = mfma_tile<256, 264>(Hh, Hl, B2h + w * 16 * 256, B2l + w * 16 * 256,
                            lq, quad, C);
#pragma unroll
    for (int r = 0; r < 4; ++r) {
      int m = quad * 4 + r;
      x[(size_t)(tok0 + m) * 64 + n] = C[r];
      xl[m * 64 + n] = C[r];
    }
  }
  __syncthreads();
  qkv_tail(xl, Sh, Sl, arena, 0, ln1_s, ln1_b, bq, bk, bv,
           qo, ko, voT, tok0, t);
}

// ---------------------------------------------------------------------------
// K4: MFMA flash attention (r8 config: 64 q/block, 1024 blocks), exp2-domain
// softmax. bias [h][q][k] pre-scaled by log2e; V pre-transposed [bh][d][l].
// ---------------------------------------------------------------------------
__global__ __launch_bounds__(256) void k_attn(
    const unsigned short* __restrict__ qg, const unsigned short* __restrict__ kg,
    const unsigned short* __restrict__ vgT, const unsigned short* __restrict__ biasT,
    float* __restrict__ og) {
  __shared__ __align__(16) unsigned short Kl[64 * 32];     // 4 KB
  __shared__ __align__(16) unsigned short VT[16 * 72];     // 2.25 KB
  __shared__ __align__(16) unsigned short Pl[4][16 * 72];  // 9 KB
  __shared__ __align__(16) unsigned short Bch[64 * 72];    // 9 KB [q][k]
  int t = threadIdx.x, w = t >> 6, lane = t & 63;
  int lq = lane & 15, quad = lane >> 4;
  int bid = blockIdx.x;
  int b = bid >> 7, h = (bid >> 4) & 7, qblk = bid & 15;
  int q0w = qblk * 64 + w * 16;
  size_t bh = (size_t)(b * 8 + h) * 1024;
  size_t bh16 = (size_t)(b * 8 + h) * 16;

  ((uint4*)Kl)[t] = uint4{0, 0, 0, 0};  // zero d16..31 pad

  short8 Qb = {};
  if (quad < 2)
    Qb = *(const short8*)(qg + (bh + q0w + lq) * 16 + quad * 8);

  float m = -1e30f, l = 0.0f;
  floatx4 O = {0.0f, 0.0f, 0.0f, 0.0f};

  // staging assignments (all vectorized)
  int key = t >> 2, dp = (t & 3) * 4;        // K: 1 uint2 / thread
  int drow = t >> 4, vcol = (t & 15) * 4;    // V^T: 1 uint2 / thread
  int qrow = t >> 2, bcol = (t & 3) * 16;    // bias: 2 uint4 / thread (16 ush)
  const unsigned short* kgp = kg + (bh + key) * 16 + dp;
  const unsigned short* vgp = vgT + (bh16 + drow) * 1024 + vcol;
  const unsigned short* bgp =
      biasT + ((size_t)(h * 1024 + qblk * 64 + qrow)) * 1024 + bcol;

  uint2 kpre = *(const uint2*)(kgp);
  uint2 vpre = *(const uint2*)(vgp);
  uint4 bpre0 = *(const uint4*)(bgp);
  uint4 bpre1 = *(const uint4*)(bgp + 8);

#pragma unroll 1
  for (int kc = 0; kc < 1024; kc += 64) {
    __syncthreads();
    *(uint2*)(Kl + key * 32 + dp) = kpre;
    *(uint2*)(VT + drow * 72 + vcol) = vpre;
    *(uint4*)(Bch + qrow * 72 + bcol) = bpre0;
    *(uint4*)(Bch + qrow * 72 + bcol + 8) = bpre1;
    __syncthreads();
    if (kc + 64 < 1024) {
      kpre = *(const uint2*)(kgp + (size_t)(kc + 64) * 16);
      vpre = *(const uint2*)(vgp + (kc + 64));
      bpre0 = *(const uint4*)(bgp + (kc + 64));
      bpre1 = *(const uint4*)(bgp + (kc + 64) + 8);
    }
    // QK^T (transposed) + bias; scores in log2 domain
    float s[16];
#pragma unroll
    for (int tile = 0; tile < 4; ++tile) {
      short8 A = *(const short8*)(Kl + (tile * 16 + lq) * 32 + quad * 8);
      floatx4 c = {0.0f, 0.0f, 0.0f, 0.0f};
      c = __builtin_amdgcn_mfma_f32_16x16x32_bf16(A, Qb, c, 0, 0, 0);
      ushort4 bb = *(const ushort4*)(Bch + (w * 16 + lq) * 72 +
                                     tile * 16 + quad * 4);
      s[tile * 4 + 0] = fmaf(c[0], 0.25f * LOG2E, bf2f(bb.x));
      s[tile * 4 + 1] = fmaf(c[1], 0.25f * LOG2E, bf2f(bb.y));
      s[tile * 4 + 2] = fmaf(c[2], 0.25f * LOG2E, bf2f(bb.z));
      s[tile * 4 + 3] = fmaf(c[3], 0.25f * LOG2E, bf2f(bb.w));
    }
    // online softmax in exp2 domain (state keyed by column q = lane&15)
    float cm = s[0];
#pragma unroll
    for (int i = 1; i < 16; ++i) cm = fmaxf(cm, s[i]);
    cm = fmaxf(cm, __shfl_xor(cm, 16, 64));
    cm = fmaxf(cm, __shfl_xor(cm, 32, 64));
    float mnew = fmaxf(m, cm);
    float alpha = exp2f(m - mnew);
    float p[16], psum = 0.0f;
#pragma unroll
    for (int i = 0; i < 16; ++i) {
      p[i] = exp2f(s[i] - mnew);
      psum += p[i];
    }
    psum += __shfl_xor(psum, 16, 64);
    psum += __shfl_xor(psum, 32, 64);
    l = l * alpha + psum;
    m = mnew;
    // P -> bf16 -> per-wave LDS (A-layout bounce)
    unsigned short* pw = &Pl[w][lq * 72];
#pragma unroll
    for (int tile = 0; tile < 4; ++tile) {
      uint2 pk;
      pk.x = (unsigned)f2bf(p[tile * 4 + 0]) | ((unsigned)f2bf(p[tile * 4 + 1]) << 16);
      pk.y = (unsigned)f2bf(p[tile * 4 + 2]) | ((unsigned)f2bf(p[tile * 4 + 3]) << 16);
      *(uint2*)(pw + tile * 16 + quad * 4) = pk;
    }
    asm volatile("s_waitcnt lgkmcnt(0)" ::: "memory");
    // rescale O (rows keyed q = quad*4+r)
#pragma unroll
    for (int r = 0; r < 4; ++r) {
      int idx = (quad * 4 + r) * 4;
      float ar = __uint_as_float(
          __builtin_amdgcn_ds_bpermute(idx, __float_as_uint(alpha)));
      O[r] *= ar;
    }
    // PV: 2 MFMAs (K=32 keys each)
#pragma unroll
    for (int i = 0; i < 2; ++i) {
      short8 Pa = *(const short8*)(pw + i * 32 + quad * 8);
      short8 Vb = *(const short8*)(&VT[lq * 72 + i * 32 + quad * 8]);
      O = __builtin_amdgcn_mfma_f32_16x16x32_bf16(Pa, Vb, O, 0, 0, 0);
    }
  }
  float linv = 1.0f / l;
#pragma unroll
  for (int r = 0; r < 4; ++r) {
    int idx = (quad * 4 + r) * 4;
    float lr = __uint_as_float(
        __builtin_amdgcn_ds_bpermute(idx, __float_as_uint(linv)));
    og[((size_t)(b * 1024 + q0w + quad * 4 + r)) * 128 + h * 16 + lq] = O[r] * lr;
  }
}

// Shared proj+LN2+FFN body. Returns with xl holding the post-FFN x rows.
__device__ __forceinline__ void pf_body(
    const float* __restrict__ ob, const unsigned short* __restrict__ arena,
    const float* __restrict__ bo, float* __restrict__ x,
    const float* __restrict__ ln_s, const float* __restrict__ ln_b,
    const float* __restrict__ b1, const float* __restrict__ b2, int lay,
    unsigned short* Ah, unsigned short* Al, unsigned short* Sh,
    unsigned short* Sl, unsigned short* Hh, unsigned short* Hl, float* xl,
    int tok0, int t, bool write_x) {
  int w = t >> 6, lane = t & 63;
  int lq = lane & 15, quad = lane >> 4;
  const unsigned short* labase = arena + OFF_LAY0 + lay * LAY_STRIDE;
  // stage attn-o split
  for (int idx = t * 4; idx < 2048; idx += 1024) {
    int row = idx >> 7, col = idx & 127;
    float4 v = *(const float4*)(ob + (size_t)(tok0 + row) * 128 + col);
    unsigned short h0, e0, h1, e1, h2, e2, h3, e3;
    split_bf(v.x, h0, e0); split_bf(v.y, h1, e1);
    split_bf(v.z, h2, e2); split_bf(v.w, h3, e3);
    unsigned* ph = (unsigned*)(Ah + row * 136 + col);
    ph[0] = (unsigned)h0 | ((unsigned)h1 << 16);
    ph[1] = (unsigned)h2 | ((unsigned)h3 << 16);
    unsigned* pl = (unsigned*)(Al + row * 136 + col);
    pl[0] = (unsigned)e0 | ((unsigned)e1 << 16);
    pl[1] = (unsigned)e2 | ((unsigned)e3 << 16);
  }
  __syncthreads();
  // proj: 128 -> 64, + residual -> xl
  {
    const unsigned short* Bh = labase + OFF_WO;
    const unsigned short* Bl = Bh + 8192;
    int n = w * 16 + lq;
    float bb = bo[lay * 64 + n];
    floatx4 C = {bb, bb, bb, bb};
    C = mfma_tile<128, 136>(Ah, Al, Bh + w * 16 * 128, Bl + w * 16 * 128,
                            lq, quad, C);
#pragma unroll
    for (int r = 0; r < 4; ++r) {
      int m = quad * 4 + r;
      xl[m * 64 + n] = x[(size_t)(tok0 + m) * 64 + n] + C[r];
    }
  }
  __syncthreads();
  // LN2 -> Sh/Sl
  {
    float ss = ln_s[lay * 64 + lane], sb = ln_b[lay * 64 + lane];
#pragma unroll
    for (int tk = 0; tk < 4; ++tk) {
      int tok = w * 4 + tk;
      float v = xl[tok * 64 + lane];
      float mean = wave_reduce_sum(v) * 0.015625f;
      float d = v - mean;
      float var = wave_reduce_sum(d * d) * 0.015625f;
      float hv = d * rsqrtf(var + 1e-6f) * ss + sb;
      unsigned short hi, lo;
      split_bf(hv, hi, lo);
      Sh[tok * 72 + lane] = hi;
      Sl[tok * 72 + lane] = lo;
    }
  }
  __syncthreads();
  // FFN G1: 64 -> 256, gelu
  {
    const unsigned short* Bh = labase + OFF_W1;
    const unsigned short* Bl = Bh + 16384;
#pragma unroll
    for (int j = 0; j < 4; ++j) {
      int tl = w * 4 + j, n = tl * 16 + lq;
      float bb = b1[lay * 256 + n];
      floatx4 C = {bb, bb, bb, bb};
      C = mfma_tile<64, 72>(Sh, Sl, Bh + tl * 16 * 64, Bl + tl * 16 * 64,
                            lq, quad, C);
#pragma unroll
      for (int r = 0; r < 4; ++r) {
        float g = gelu_tanh(C[r]);
        unsigned short hi, lo;
        split_bf(g, hi, lo);
        Hh[(quad * 4 + r) * 264 + n] = hi;
        Hl[(quad * 4 + r) * 264 + n] = lo;
      }
    }
  }
  __syncthreads();
  // FFN G2: 256 -> 64, + residual -> xl (and optionally x)
  {
    const unsigned short* Bh = labase + OFF_W2;
    const unsigned short* Bl = Bh + 16384;
    int n = w * 16 + lq;
    float bb = b2[lay * 64 + n];
    floatx4 C = {bb, bb, bb, bb};
    C = mfma_tile<256, 264>(Hh, Hl, Bh + w * 16 * 256, Bl + w * 16 * 256,
                            lq, quad, C);
#pragma unroll
    for (int r = 0; r < 4; ++r) {
      int m = quad * 4 + r;
      float xv = xl[m * 64 + n] + C[r];
      xl[m * 64 + n] = xv;
      if (write_x) x[(size_t)(tok0 + m) * 64 + n] = xv;
    }
  }
  __syncthreads();
}

// ---------------------------------------------------------------------------
// K5a: proj+LN2+FFN (layer lay) then LN1+QKV (layer lay+1).
// ---------------------------------------------------------------------------
__global__ __launch_bounds__(256) void k_pf_qkv(
    const float* __restrict__ ob, const unsigned short* __restrict__ arena,
    const float* __restrict__ bo, float* __restrict__ x,
    const float* __restrict__ ln2_s, const float* __restrict__ ln2_b,
    const float* __restrict__ b1, const float* __restrict__ b2, int lay,
    const float* __restrict__ ln1_s, const float* __restrict__ ln1_b,
    const float* __restrict__ bq, const float* __restrict__ bk,
    const float* __restrict__ bv, unsigned short* __restrict__ qo,
    unsigned short* __restrict__ ko, unsigned short* __restrict__ voT) {
  __shared__ __align__(16) unsigned short Ah[16 * 136], Al[16 * 136];
  __shared__ __align__(16) unsigned short Sh[16 * 72], Sl[16 * 72];
  __shared__ __align__(16) unsigned short Hh[16 * 264], Hl[16 * 264];
  __shared__ float xl[16 * 64];
  int t = threadIdx.x;
  int tok0 = blockIdx.x * 16;
  pf_body(ob, arena, bo, x, ln2_s, ln2_b, b1, b2, lay,
          Ah, Al, Sh, Sl, Hh, Hl, xl, tok0, t, true);
  qkv_tail(xl, Sh, Sl, arena, lay + 1, ln1_s, ln1_b, bq, bk, bv,
           qo, ko, voT, tok0, t);
}

// ---------------------------------------------------------------------------
// K5b: proj+LN2+FFN (last layer) then head MLP.
// ---------------------------------------------------------------------------
__global__ __launch_bounds__(256) void k_pf_head(
    const float* __restrict__ ob, const unsigned short* __restrict__ arena,
    const float* __restrict__ bo, float* __restrict__ x,
    const float* __restrict__ ln2_s, const float* __restrict__ ln2_b,
    const float* __restrict__ b1, const float* __restrict__ b2, int lay,
    const float* __restrict__ bh1, const float* __restrict__ bh2,
    const float* __restrict__ Wh3, const float* __restrict__ bh3,
    float* __restrict__ out) {
  __shared__ __align__(16) unsigned short Ah[16 * 136], Al[16 * 136];
  __shared__ __align__(16) unsigned short Sh[16 * 72], Sl[16 * 72];
  __shared__ __align__(16) unsigned short Hh[16 * 264], Hl[16 * 264];
  __shared__ float xl[16 * 64];
  int t = threadIdx.x, w = t >> 6, lane = t & 63;
  int lq = lane & 15, quad = lane >> 4;
  int tok0 = blockIdx.x * 16;
  pf_body(ob, arena, bo, x, ln2_s, ln2_b, b1, b2, lay,
          Ah, Al, Sh, Sl, Hh, Hl, xl, tok0, t, false);
  // split raw x -> Sh/Sl
#pragma unroll
  for (int tk = 0; tk < 4; ++tk) {
    int tok = w * 4 + tk;
    unsigned short hi, lo;
    split_bf(xl[tok * 64 + lane], hi, lo);
    Sh[tok * 72 + lane] = hi;
    Sl[tok * 72 + lane] = lo;
  }
  __syncthreads();
  // head G1: 64 -> 256, gelu
  {
    const unsigned short* Bh = arena + OFF_WH1;
    const unsigned short* Bl = Bh + 16384;
#pragma unroll
    for (int j = 0; j < 4; ++j) {
      int tl = w * 4 + j, n = tl * 16 + lq;
      float bb = bh1[n];
      floatx4 C = {bb, bb, bb, bb};
      C = mfma_tile<64, 72>(Sh, Sl, Bh + tl * 16 * 64, Bl + tl * 16 * 64,
                            lq, quad, C);
#pragma unroll
      for (int r = 0; r < 4; ++r) {
        float g = gelu_tanh(C[r]);
        unsigned short hi, lo;
        split_bf(g, hi, lo);
        Hh[(quad * 4 + r) * 264 + n] = hi;
        Hl[(quad * 4 + r) * 264 + n] = lo;
      }
    }
  }
  __syncthreads();
  // head G2: 256 -> 64, gelu -> xl (reused as h2s)
  {
    const unsigned short* Bh = arena + OFF_WH2;
    const unsigned short* Bl = Bh + 16384;
    int n = w * 16 + lq;
    float bb = bh2[n];
    floatx4 C = {bb, bb, bb, bb};
    C = mfma_tile<256, 264>(Hh, Hl, Bh + w * 16 * 256, Bl + w * 16 * 256,
                            lq, quad, C);
    __syncthreads();
#pragma unroll
    for (int r = 0; r < 4; ++r)
      xl[(quad * 4 + r) * 64 + n] = gelu_tanh(C[r]);
  }
  __syncthreads();
  // head G3: dot with Wh3
  float wv3 = Wh3[lane];
#pragma unroll
  for (int tk = 0; tk < 4; ++tk) {
    int tok = w * 4 + tk;
    float v = xl[tok * 64 + lane] * wv3;
    float sum = wave_reduce_sum(v);
    if (lane == 0) out[tok0 + tok] = sum + bh3[0];
  }
}

// ---------------------------------------------------------------------------
extern "C" void kernel_launch(void* const* d_in, const int* in_sizes, int n_in,
                              void* d_out, int out_size, void* d_ws, size_t ws_size,
                              hipStream_t stream) {
  const float* z      = (const float*)d_in[0];
  const float* cond   = (const float*)d_in[1];
  const float* s      = (const float*)d_in[2];
  const float* embed  = (const float*)d_in[3];
  const float* Win1   = (const float*)d_in[4];
  const float* bin1   = (const float*)d_in[5];
  const float* Win2   = (const float*)d_in[6];
  const float* bin2   = (const float*)d_in[7];
  const float* ln1_s  = (const float*)d_in[8];
  const float* ln1_b  = (const float*)d_in[9];
  const float* ln2_s  = (const float*)d_in[10];
  const float* ln2_b  = (const float*)d_in[11];
  const float* Wq     = (const float*)d_in[12];
  const float* bq     = (const float*)d_in[13];
  const float* Wk     = (const float*)d_in[14];
  const float* bk     = (const float*)d_in[15];
  const float* Wv     = (const float*)d_in[16];
  const float* bv     = (const float*)d_in[17];
  const float* Wo     = (const float*)d_in[18];
  const float* bo     = (const float*)d_in[19];
  const float* rbf_c  = (const float*)d_in[20];
  const float* rbf_lw = (const float*)d_in[21];
  const float* rbf_w  = (const float*)d_in[22];
  const float* rbf_b  = (const float*)d_in[23];
  const float* W1     = (const float*)d_in[24];
  const float* b1     = (const float*)d_in[25];
  const float* W2     = (const float*)d_in[26];
  const float* b2     = (const float*)d_in[27];
  const float* Wh1    = (const float*)d_in[28];
  const float* bh1    = (const float*)d_in[29];
  const float* Wh2    = (const float*)d_in[30];
  const float* bh2    = (const float*)d_in[31];
  const float* Wh3    = (const float*)d_in[32];
  const float* bh3    = (const float*)d_in[33];

  char* base = (char*)d_ws;
  float*          x     = (float*)(base);                          // 2 MB
  unsigned short* qb    = (unsigned short*)(base + (2u << 20));    // 2 MB
  unsigned short* kb    = (unsigned short*)(base + (4u << 20));    // 2 MB
  unsigned short* vbT   = (unsigned short*)(base + (6u << 20));    // 2 MB
  float*          ob    = (float*)(base + (8u << 20));             // 4 MB
  unsigned short* biasT = (unsigned short*)(base + (12u << 20));   // 2 x 16 MB
  unsigned short* arena = (unsigned short*)(base + (48u << 20));   // ~832 KB

  PrepArgs pa;
  auto set = [&](int i, const float* sp, int K, int N, int dst) {
    pa.src[i] = sp; pa.Kd[i] = K; pa.Nd[i] = N; pa.dst[i] = dst;
    pa.elems[i] = K * N;
  };
  set(0, Win1, 128, 256, OFF_WIN1);
  set(1, Win2, 256, 64, OFF_WIN2);
  for (int lay = 0; lay < 2; ++lay) {
    int lb = OFF_LAY0 + lay * LAY_STRIDE;
    set(2 + lay * 6, Wq + lay * 8192, 64, 128, lb + OFF_WQ);
    set(3 + lay * 6, Wk + lay * 8192, 64, 128, lb + OFF_WK);
    set(4 + lay * 6, Wv + lay * 8192, 64, 128, lb + OFF_WV);
    set(5 + lay * 6, Wo + lay * 8192, 128, 64, lb + OFF_WO);
    set(6 + lay * 6, W1 + lay * 16384, 64, 256, lb + OFF_W1);
    set(7 + lay * 6, W2 + lay * 16384, 256, 64, lb + OFF_W2);
  }
  set(14, Wh1, 64, 256, OFF_WH1);
  set(15, Wh2, 256, 64, OFF_WH2);

  k_prep_bias<<<2048 + 8192, 256, 0, stream>>>(pa, arena, s, rbf_c, rbf_lw,
                                               rbf_w, rbf_b, biasT);
  k_in_qkv<<<512, 256, 0, stream>>>(embed, z, cond, arena, bin1, bin2, x,
                                    ln1_s, ln1_b, bq, bk, bv, qb, kb, vbT);
  k_attn<<<1024, 256, 0, stream>>>(qb, kb, vbT, biasT, ob);
  k_pf_qkv<<<512, 256, 0, stream>>>(ob, arena, bo, x, ln2_s, ln2_b, b1, b2, 0,
                                    ln1_s, ln1_b, bq, bk, bv, qb, kb, vbT);
  k_attn<<<1024, 256, 0, stream>>>(qb, kb, vbT,
                                   biasT + (size_t)8 * 1024 * 1024, ob);
  k_pf_head<<<512, 256, 0, stream>>>(ob, arena, bo, x, ln2_s, ln2_b, b1, b2, 1,
                                     bh1, bh2, Wh3, bh3, (float*)d_out);
}

// Round 11
// 267.382 us; speedup vs baseline: 1.0674x; 1.0674x over previous
//
#include <hip/hip_runtime.h>
#include <hip/hip_bf16.h>

// Problem constants (reference: B=8, L=1024, C=4, D=64, H=8, NB=2, K=16)
#define BB   8
#define LL   1024
#define DD   64
#define D2   128
#define D4   256
#define HH   8
#define DH   16

typedef __attribute__((ext_vector_type(8))) short short8;   // 8 bf16 (4 VGPRs)
typedef __attribute__((ext_vector_type(4))) float floatx4;  // MFMA C/D

#define LOG2E 1.4426950408889634f
// exponent offset -24 folded into the QK^T accumulator: -24/(0.25*LOG2E)
#define QK_SEED -66.54214054f

// bf16 split-weight arena offsets (elements)
#define OFF_WIN1   0        // [256][128] hi, lo at +32768
#define OFF_WIN2   65536    // [64][256]  hi, lo at +16384
#define OFF_LAY0   98304
#define LAY_STRIDE 131072
#define OFF_WQ     0        // [128][64] hi, lo +8192
#define OFF_WK     16384
#define OFF_WV     32768
#define OFF_WO     49152    // [64][128] hi, lo +8192
#define OFF_W1     65536    // [256][64] hi, lo +16384
#define OFF_W2     98304    // [64][256] hi, lo +16384
#define OFF_WH1    360448   // [256][64] hi, lo +16384
#define OFF_WH2    393216   // [64][256] hi, lo +16384

__device__ __forceinline__ float gelu_tanh(float u) {
  float t = tanhf(0.7978845608028654f * (u + 0.044715f * u * u * u));
  return 0.5f * u * (1.0f + t);
}

__device__ __forceinline__ float wave_reduce_sum(float v) {
#pragma unroll
  for (int m = 32; m >= 1; m >>= 1) v += __shfl_xor(v, m, 64);
  return v;
}

__device__ __forceinline__ unsigned short f2bf(float x) {  // RNE
  unsigned u = __float_as_uint(x);
  u += 0x7fffu + ((u >> 16) & 1u);
  return (unsigned short)(u >> 16);
}

__device__ __forceinline__ float bf2f(unsigned short x) {
  return __uint_as_float(((unsigned)x) << 16);
}

__device__ __forceinline__ void split_bf(float v, unsigned short& hi,
                                         unsigned short& lo) {
  hi = f2bf(v);
  lo = f2bf(v - bf2f(hi));
}

// pack two fp32 -> two bf16 (round-half-up) in one v_perm_b32
__device__ __forceinline__ unsigned pack_bf2(float a, float b) {
  unsigned ua = __float_as_uint(a) + 0x8000u;
  unsigned ub = __float_as_uint(b) + 0x8000u;
  return __builtin_amdgcn_perm(ub, ua, 0x07060302u);  // (bf(b)<<16)|bf(a)
}

// 16x16 output tile over K with 3-term bf16 split (single accumulator — the
// 3-acc ILP variant regressed dense kernels by ~10us in r10).
template <int K, int KP>
__device__ __forceinline__ floatx4 mfma_tile(
    const unsigned short* Ah, const unsigned short* Al,
    const unsigned short* __restrict__ Bh, const unsigned short* __restrict__ Bl,
    int lq, int quad, floatx4 C) {
#pragma unroll
  for (int kk = 0; kk < K; kk += 32) {
    short8 ah = *(const short8*)(Ah + lq * KP + kk + quad * 8);
    short8 al = *(const short8*)(Al + lq * KP + kk + quad * 8);
    short8 bh = *(const short8*)(Bh + lq * K + kk + quad * 8);
    short8 bl = *(const short8*)(Bl + lq * K + kk + quad * 8);
    C = __builtin_amdgcn_mfma_f32_16x16x32_bf16(ah, bh, C, 0, 0, 0);
    C = __builtin_amdgcn_mfma_f32_16x16x32_bf16(al, bh, C, 0, 0, 0);
    C = __builtin_amdgcn_mfma_f32_16x16x32_bf16(ah, bl, C, 0, 0, 0);
  }
  return C;
}

// ---------------------------------------------------------------------------
// K0: merged weight prep (bid<2048) + RBF bias (rest). Flat grid.
// bias stored PRE-SCALED by log2(e) so attn softmax runs in exp2 domain.
// ---------------------------------------------------------------------------
struct PrepArgs {
  const float* src[16];
  int Kd[16], Nd[16], dst[16], elems[16];
};

__global__ __launch_bounds__(256) void k_prep_bias(
    PrepArgs a, unsigned short* __restrict__ arena,
    const float* __restrict__ s, const float* __restrict__ rbf_c,
    const float* __restrict__ rbf_logw, const float* __restrict__ rbf_w,
    const float* __restrict__ rbf_b, unsigned short* __restrict__ biasT) {
  int bid = blockIdx.x, t = threadIdx.x;
  if (bid < 2048) {
    int mid = bid >> 7;
    int e = (bid & 127) * 256 + t;
    int KN = a.elems[mid];
    if (e >= KN) return;
    int K = a.Kd[mid], N = a.Nd[mid];
    int n = e / K, k = e - n * K;
    float wv = a.src[mid][k * N + n];
    unsigned short hi, lo;
    split_bf(wv, hi, lo);
    arena[a.dst[mid] + e] = hi;
    arena[a.dst[mid] + KN + e] = lo;
    return;
  }
  int rem = bid - 2048;
  int lay = rem >> 12;
  int id = (rem & 4095) * 256 + t;
  int q = id >> 10, k = id & 1023;
  float dd = s[q] - s[k];  // dist[q,k] = s[q]-s[k]
  float acc[8];
#pragma unroll
  for (int h = 0; h < 8; ++h) acc[h] = rbf_b[lay * 8 + h];
#pragma unroll 1
  for (int f = 0; f < 16; ++f) {
    float c = rbf_c[lay * 16 + f];
    float inv2w2 = 0.5f * __expf(-2.0f * rbf_logw[lay * 16 + f]);
    float e = dd - c;
    float ph = __expf(-e * e * inv2w2);
#pragma unroll
    for (int h = 0; h < 8; ++h)
      acc[h] = fmaf(ph, rbf_w[lay * 128 + f * 8 + h], acc[h]);
  }
  unsigned short* bT = biasT + (size_t)lay * 8 * 1024 * 1024;
#pragma unroll
  for (int h = 0; h < 8; ++h)
    bT[(size_t)(h * 1024 + q) * 1024 + k] = f2bf(acc[h] * LOG2E);
}

// Shared QKV tail: LN(xl) -> split -> 3 MFMA mats -> q/k global, v transposed.
__device__ __forceinline__ void qkv_tail(
    const float* xl, unsigned short* Sh, unsigned short* Sl,
    const unsigned short* __restrict__ arena, int lay,
    const float* __restrict__ ln_s, const float* __restrict__ ln_b,
    const float* __restrict__ bq, const float* __restrict__ bk,
    const float* __restrict__ bv, unsigned short* __restrict__ qo,
    unsigned short* __restrict__ ko, unsigned short* __restrict__ voT,
    int tok0, int t) {
  int w = t >> 6, lane = t & 63;
  int lq = lane & 15, quad = lane >> 4;
  float ss = ln_s[lay * 64 + lane], sb = ln_b[lay * 64 + lane];
#pragma unroll
  for (int tk = 0; tk < 4; ++tk) {
    int tok = w * 4 + tk;
    float v = xl[tok * 64 + lane];
    float mean = wave_reduce_sum(v) * 0.015625f;
    float d = v - mean;
    float var = wave_reduce_sum(d * d) * 0.015625f;
    float hv = d * rsqrtf(var + 1e-6f) * ss + sb;
    unsigned short hi, lo;
    split_bf(hv, hi, lo);
    Sh[tok * 72 + lane] = hi;
    Sl[tok * 72 + lane] = lo;
  }
  __syncthreads();
  int b = tok0 >> 10, l0 = tok0 & 1023;
#pragma unroll 1
  for (int mat = 0; mat < 3; ++mat) {
    const unsigned short* Bh =
        arena + OFF_LAY0 + lay * LAY_STRIDE + mat * 16384;
    const unsigned short* Bl = Bh + 8192;
    const float* bias = (mat == 0 ? bq : mat == 1 ? bk : bv) + lay * 128;
#pragma unroll
    for (int j = 0; j < 2; ++j) {
      int tl = w + j * 4;  // head index
      int n = tl * 16 + lq;
      float bb = bias[n];
      floatx4 C = {bb, bb, bb, bb};
      C = mfma_tile<64, 72>(Sh, Sl, Bh + tl * 16 * 64, Bl + tl * 16 * 64,
                            lq, quad, C);
      if (mat < 2) {
        unsigned short* outp = (mat == 0 ? qo : ko);
        size_t basea = ((size_t)(b * 8 + tl) * 1024 + l0 + quad * 4) * 16 + lq;
#pragma unroll
        for (int r = 0; r < 4; ++r)
          outp[basea + (size_t)r * 16] = f2bf(C[r]);
      } else {
        size_t basev = ((size_t)(b * 8 + tl) * 16 + lq) * 1024 + l0 + quad * 4;
#pragma unroll
        for (int r = 0; r < 4; ++r)
          voT[basev + r] = f2bf(C[r]);
      }
    }
  }
}

// ---------------------------------------------------------------------------
// K1: input MLP + LN1 + QKV (layer 0). 16 tokens/block.
// ---------------------------------------------------------------------------
__global__ __launch_bounds__(256) void k_in_qkv(
    const float* __restrict__ embed, const float* __restrict__ z,
    const float* __restrict__ cond, const unsigned short* __restrict__ arena,
    const float* __restrict__ bin1, const float* __restrict__ bin2,
    float* __restrict__ x, const float* __restrict__ ln1_s,
    const float* __restrict__ ln1_b, const float* __restrict__ bq,
    const float* __restrict__ bk, const float* __restrict__ bv,
    unsigned short* __restrict__ qo, unsigned short* __restrict__ ko,
    unsigned short* __restrict__ voT) {
  __shared__ __align__(16) unsigned short Ah[16 * 136], Al[16 * 136];
  __shared__ __align__(16) unsigned short Hh[16 * 264], Hl[16 * 264];
  __shared__ __align__(16) unsigned short Sh[16 * 72], Sl[16 * 72];
  __shared__ float xl[16 * 64];
  int t = threadIdx.x, w = t >> 6, lane = t & 63;
  int lq = lane & 15, quad = lane >> 4;
  int tok0 = blockIdx.x * 16;
  for (int idx = t; idx < 2048; idx += 256) {
    int tok = idx >> 7, dim = idx & 127;
    int bl = tok0 + tok, l = bl & (LL - 1);
    float v;
    if (dim < 123) v = embed[l * 123 + dim];
    else if (dim == 123) v = z[bl];
    else v = cond[dim - 124];
    unsigned short hi, lo;
    split_bf(v, hi, lo);
    Ah[tok * 136 + dim] = hi;
    Al[tok * 136 + dim] = lo;
  }
  __syncthreads();
  // G1: 128 -> 256, gelu
  const unsigned short* B1h = arena + OFF_WIN1;
  const unsigned short* B1l = B1h + 32768;
#pragma unroll
  for (int j = 0; j < 4; ++j) {
    int tl = w * 4 + j, n = tl * 16 + lq;
    float bb = bin1[n];
    floatx4 C = {bb, bb, bb, bb};
    C = mfma_tile<128, 136>(Ah, Al, B1h + tl * 16 * 128, B1l + tl * 16 * 128,
                            lq, quad, C);
#pragma unroll
    for (int r = 0; r < 4; ++r) {
      float g = gelu_tanh(C[r]);
      unsigned short hi, lo;
      split_bf(g, hi, lo);
      Hh[(quad * 4 + r) * 264 + n] = hi;
      Hl[(quad * 4 + r) * 264 + n] = lo;
    }
  }
  __syncthreads();
  // G2: 256 -> 64 -> x (global + xl)
  const unsigned short* B2h = arena + OFF_WIN2;
  const unsigned short* B2l = B2h + 16384;
  {
    int n = w * 16 + lq;
    float bb = bin2[n];
    floatx4 C = {bb, bb, bb, bb};
    C = mfma_tile<256, 264>(Hh, Hl, B2h + w * 16 * 256, B2l + w * 16 * 256,
                            lq, quad, C);
#pragma unroll
    for (int r = 0; r < 4; ++r) {
      int m = quad * 4 + r;
      x[(size_t)(tok0 + m) * 64 + n] = C[r];
      xl[m * 64 + n] = C[r];
    }
  }
  __syncthreads();
  qkv_tail(xl, Sh, Sl, arena, 0, ln1_s, ln1_b, bq, bk, bv,
           qo, ko, voT, tok0, t);
}

// ---------------------------------------------------------------------------
// K4: MFMA flash attention, no-max softmax (fixed exponent offset -24 folded
// into the QK^T accumulator seed). 64 q/block, 1024 blocks, exp2 domain.
// bias [h][q][k] pre-scaled by log2e; V pre-transposed [bh][d][l].
// ---------------------------------------------------------------------------
__global__ __launch_bounds__(256) void k_attn(
    const unsigned short* __restrict__ qg, const unsigned short* __restrict__ kg,
    const unsigned short* __restrict__ vgT, const unsigned short* __restrict__ biasT,
    float* __restrict__ og) {
  __shared__ __align__(16) unsigned short Kl[64 * 32];     // 4 KB
  __shared__ __align__(16) unsigned short VT[16 * 72];     // 2.25 KB
  __shared__ __align__(16) unsigned short Pl[4][16 * 72];  // 9 KB
  __shared__ __align__(16) unsigned short Bch[64 * 72];    // 9 KB [q][k]
  int t = threadIdx.x, w = t >> 6, lane = t & 63;
  int lq = lane & 15, quad = lane >> 4;
  int bid = blockIdx.x;
  int b = bid >> 7, h = (bid >> 4) & 7, qblk = bid & 15;
  int q0w = qblk * 64 + w * 16;
  size_t bh = (size_t)(b * 8 + h) * 1024;
  size_t bh16 = (size_t)(b * 8 + h) * 16;

  ((uint4*)Kl)[t] = uint4{0, 0, 0, 0};  // zero d16..31 pad

  short8 Qb = {};
  if (quad < 2)
    Qb = *(const short8*)(qg + (bh + q0w + lq) * 16 + quad * 8);

  float l = 0.0f;
  floatx4 O = {0.0f, 0.0f, 0.0f, 0.0f};

  // staging assignments (all vectorized)
  int key = t >> 2, dp = (t & 3) * 4;        // K: 1 uint2 / thread
  int drow = t >> 4, vcol = (t & 15) * 4;    // V^T: 1 uint2 / thread
  int qrow = t >> 2, bcol = (t & 3) * 16;    // bias: 2 uint4 / thread (16 ush)
  const unsigned short* kgp = kg + (bh + key) * 16 + dp;
  const unsigned short* vgp = vgT + (bh16 + drow) * 1024 + vcol;
  const unsigned short* bgp =
      biasT + ((size_t)(h * 1024 + qblk * 64 + qrow)) * 1024 + bcol;

  uint2 kpre = *(const uint2*)(kgp);
  uint2 vpre = *(const uint2*)(vgp);
  uint4 bpre0 = *(const uint4*)(bgp);
  uint4 bpre1 = *(const uint4*)(bgp + 8);

#pragma unroll 1
  for (int kc = 0; kc < 1024; kc += 64) {
    __syncthreads();
    *(uint2*)(Kl + key * 32 + dp) = kpre;
    *(uint2*)(VT + drow * 72 + vcol) = vpre;
    *(uint4*)(Bch + qrow * 72 + bcol) = bpre0;
    *(uint4*)(Bch + qrow * 72 + bcol + 8) = bpre1;
    __syncthreads();
    if (kc + 64 < 1024) {
      kpre = *(const uint2*)(kgp + (size_t)(kc + 64) * 16);
      vpre = *(const uint2*)(vgp + (kc + 64));
      bpre0 = *(const uint4*)(bgp + (kc + 64));
      bpre1 = *(const uint4*)(bgp + (kc + 64) + 8);
    }
    // QK^T + bias -> p = exp2(s) directly (offset is in the seed)
    float psum = 0.0f;
    unsigned short* pw = &Pl[w][lq * 72];
#pragma unroll
    for (int tile = 0; tile < 4; ++tile) {
      short8 A = *(const short8*)(Kl + (tile * 16 + lq) * 32 + quad * 8);
      floatx4 c = {QK_SEED, QK_SEED, QK_SEED, QK_SEED};
      c = __builtin_amdgcn_mfma_f32_16x16x32_bf16(A, Qb, c, 0, 0, 0);
      ushort4 bb = *(const ushort4*)(Bch + (w * 16 + lq) * 72 +
                                     tile * 16 + quad * 4);
      float p0 = exp2f(fmaf(c[0], 0.25f * LOG2E, bf2f(bb.x)));
      float p1 = exp2f(fmaf(c[1], 0.25f * LOG2E, bf2f(bb.y)));
      float p2 = exp2f(fmaf(c[2], 0.25f * LOG2E, bf2f(bb.z)));
      float p3 = exp2f(fmaf(c[3], 0.25f * LOG2E, bf2f(bb.w)));
      psum += (p0 + p1) + (p2 + p3);
      uint2 pk;
      pk.x = pack_bf2(p0, p1);
      pk.y = pack_bf2(p2, p3);
      *(uint2*)(pw + tile * 16 + quad * 4) = pk;
    }
    psum += __shfl_xor(psum, 16, 64);
    psum += __shfl_xor(psum, 32, 64);
    l += psum;
    asm volatile("s_waitcnt lgkmcnt(0)" ::: "memory");
    // PV: 2 MFMAs (K=32 keys each), no rescale needed
#pragma unroll
    for (int i = 0; i < 2; ++i) {
      short8 Pa = *(const short8*)(pw + i * 32 + quad * 8);
      short8 Vb = *(const short8*)(&VT[lq * 72 + i * 32 + quad * 8]);
      O = __builtin_amdgcn_mfma_f32_16x16x32_bf16(Pa, Vb, O, 0, 0, 0);
    }
  }
  float linv = 1.0f / l;
#pragma unroll
  for (int r = 0; r < 4; ++r) {
    int idx = (quad * 4 + r) * 4;
    float lr = __uint_as_float(
        __builtin_amdgcn_ds_bpermute(idx, __float_as_uint(linv)));
    og[((size_t)(b * 1024 + q0w + quad * 4 + r)) * 128 + h * 16 + lq] = O[r] * lr;
  }
}

// Shared proj+LN2+FFN body. Returns with xl holding the post-FFN x rows.
__device__ __forceinline__ void pf_body(
    const float* __restrict__ ob, const unsigned short* __restrict__ arena,
    const float* __restrict__ bo, float* __restrict__ x,
    const float* __restrict__ ln_s, const float* __restrict__ ln_b,
    const float* __restrict__ b1, const float* __restrict__ b2, int lay,
    unsigned short* Ah, unsigned short* Al, unsigned short* Sh,
    unsigned short* Sl, unsigned short* Hh, unsigned short* Hl, float* xl,
    int tok0, int t, bool write_x) {
  int w = t >> 6, lane = t & 63;
  int lq = lane & 15, quad = lane >> 4;
  const unsigned short* labase = arena + OFF_LAY0 + lay * LAY_STRIDE;
  // stage attn-o split
  for (int idx = t * 4; idx < 2048; idx += 1024) {
    int row = idx >> 7, col = idx & 127;
    float4 v = *(const float4*)(ob + (size_t)(tok0 + row) * 128 + col);
    unsigned short h0, e0, h1, e1, h2, e2, h3, e3;
    split_bf(v.x, h0, e0); split_bf(v.y, h1, e1);
    split_bf(v.z, h2, e2); split_bf(v.w, h3, e3);
    unsigned* ph = (unsigned*)(Ah + row * 136 + col);
    ph[0] = (unsigned)h0 | ((unsigned)h1 << 16);
    ph[1] = (unsigned)h2 | ((unsigned)h3 << 16);
    unsigned* pl = (unsigned*)(Al + row * 136 + col);
    pl[0] = (unsigned)e0 | ((unsigned)e1 << 16);
    pl[1] = (unsigned)e2 | ((unsigned)e3 << 16);
  }
  __syncthreads();
  // proj: 128 -> 64, + residual -> xl
  {
    const unsigned short* Bh = labase + OFF_WO;
    const unsigned short* Bl = Bh + 8192;
    int n = w * 16 + lq;
    float bb = bo[lay * 64 + n];
    floatx4 C = {bb, bb, bb, bb};
    C = mfma_tile<128, 136>(Ah, Al, Bh + w * 16 * 128, Bl + w * 16 * 128,
                            lq, quad, C);
#pragma unroll
    for (int r = 0; r < 4; ++r) {
      int m = quad * 4 + r;
      xl[m * 64 + n] = x[(size_t)(tok0 + m) * 64 + n] + C[r];
    }
  }
  __syncthreads();
  // LN2 -> Sh/Sl
  {
    float ss = ln_s[lay * 64 + lane], sb = ln_b[lay * 64 + lane];
#pragma unroll
    for (int tk = 0; tk < 4; ++tk) {
      int tok = w * 4 + tk;
      float v = xl[tok * 64 + lane];
      float mean = wave_reduce_sum(v) * 0.015625f;
      float d = v - mean;
      float var = wave_reduce_sum(d * d) * 0.015625f;
      float hv = d * rsqrtf(var + 1e-6f) * ss + sb;
      unsigned short hi, lo;
      split_bf(hv, hi, lo);
      Sh[tok * 72 + lane] = hi;
      Sl[tok * 72 + lane] = lo;
    }
  }
  __syncthreads();
  // FFN G1: 64 -> 256, gelu
  {
    const unsigned short* Bh = labase + OFF_W1;
    const unsigned short* Bl = Bh + 16384;
#pragma unroll
    for (int j = 0; j < 4; ++j) {
      int tl = w * 4 + j, n = tl * 16 + lq;
      float bb = b1[lay * 256 + n];
      floatx4 C = {bb, bb, bb, bb};
      C = mfma_tile<64, 72>(Sh, Sl, Bh + tl * 16 * 64, Bl + tl * 16 * 64,
                            lq, quad, C);
#pragma unroll
      for (int r = 0; r < 4; ++r) {
        float g = gelu_tanh(C[r]);
        unsigned short hi, lo;
        split_bf(g, hi, lo);
        Hh[(quad * 4 + r) * 264 + n] = hi;
        Hl[(quad * 4 + r) * 264 + n] = lo;
      }
    }
  }
  __syncthreads();
  // FFN G2: 256 -> 64, + residual -> xl (and optionally x)
  {
    const unsigned short* Bh = labase + OFF_W2;
    const unsigned short* Bl = Bh + 16384;
    int n = w * 16 + lq;
    float bb = b2[lay * 64 + n];
    floatx4 C = {bb, bb, bb, bb};
    C = mfma_tile<256, 264>(Hh, Hl, Bh + w * 16 * 256, Bl + w * 16 * 256,
                            lq, quad, C);
#pragma unroll
    for (int r = 0; r < 4; ++r) {
      int m = quad * 4 + r;
      float xv = xl[m * 64 + n] + C[r];
      xl[m * 64 + n] = xv;
      if (write_x) x[(size_t)(tok0 + m) * 64 + n] = xv;
    }
  }
  __syncthreads();
}

// ---------------------------------------------------------------------------
// K5a: proj+LN2+FFN (layer lay) then LN1+QKV (layer lay+1).
// ---------------------------------------------------------------------------
__global__ __launch_bounds__(256) void k_pf_qkv(
    const float* __restrict__ ob, const unsigned short* __restrict__ arena,
    const float* __restrict__ bo, float* __restrict__ x,
    const float* __restrict__ ln2_s, const float* __restrict__ ln2_b,
    const float* __restrict__ b1, const float* __restrict__ b2, int lay,
    const float* __restrict__ ln1_s, const float* __restrict__ ln1_b,
    const float* __restrict__ bq, const float* __restrict__ bk,
    const float* __restrict__ bv, unsigned short* __restrict__ qo,
    unsigned short* __restrict__ ko, unsigned short* __restrict__ voT) {
  __shared__ __align__(16) unsigned short Ah[16 * 136], Al[16 * 136];
  __shared__ __align__(16) unsigned short Sh[16 * 72], Sl[16 * 72];
  __shared__ __align__(16) unsigned short Hh[16 * 264], Hl[16 * 264];
  __shared__ float xl[16 * 64];
  int t = threadIdx.x;
  int tok0 = blockIdx.x * 16;
  pf_body(ob, arena, bo, x, ln2_s, ln2_b, b1, b2, lay,
          Ah, Al, Sh, Sl, Hh, Hl, xl, tok0, t, true);
  qkv_tail(xl, Sh, Sl, arena, lay + 1, ln1_s, ln1_b, bq, bk, bv,
           qo, ko, voT, tok0, t);
}

// ---------------------------------------------------------------------------
// K5b: proj+LN2+FFN (last layer) then head MLP.
// ---------------------------------------------------------------------------
__global__ __launch_bounds__(256) void k_pf_head(
    const float* __restrict__ ob, const unsigned short* __restrict__ arena,
    const float* __restrict__ bo, float* __restrict__ x,
    const float* __restrict__ ln2_s, const float* __restrict__ ln2_b,
    const float* __restrict__ b1, const float* __restrict__ b2, int lay,
    const float* __restrict__ bh1, const float* __restrict__ bh2,
    const float* __restrict__ Wh3, const float* __restrict__ bh3,
    float* __restrict__ out) {
  __shared__ __align__(16) unsigned short Ah[16 * 136], Al[16 * 136];
  __shared__ __align__(16) unsigned short Sh[16 * 72], Sl[16 * 72];
  __shared__ __align__(16) unsigned short Hh[16 * 264], Hl[16 * 264];
  __shared__ float xl[16 * 64];
  int t = threadIdx.x, w = t >> 6, lane = t & 63;
  int lq = lane & 15, quad = lane >> 4;
  int tok0 = blockIdx.x * 16;
  pf_body(ob, arena, bo, x, ln2_s, ln2_b, b1, b2, lay,
          Ah, Al, Sh, Sl, Hh, Hl, xl, tok0, t, false);
  // split raw x -> Sh/Sl
#pragma unroll
  for (int tk = 0; tk < 4; ++tk) {
    int tok = w * 4 + tk;
    unsigned short hi, lo;
    split_bf(xl[tok * 64 + lane], hi, lo);
    Sh[tok * 72 + lane] = hi;
    Sl[tok * 72 + lane] = lo;
  }
  __syncthreads();
  // head G1: 64 -> 256, gelu
  {
    const unsigned short* Bh = arena + OFF_WH1;
    const unsigned short* Bl = Bh + 16384;
#pragma unroll
    for (int j = 0; j < 4; ++j) {
      int tl = w * 4 + j, n = tl * 16 + lq;
      float bb = bh1[n];
      floatx4 C = {bb, bb, bb, bb};
      C = mfma_tile<64, 72>(Sh, Sl, Bh + tl * 16 * 64, Bl + tl * 16 * 64,
                            lq, quad, C);
#pragma unroll
      for (int r = 0; r < 4; ++r) {
        float g = gelu_tanh(C[r]);
        unsigned short hi, lo;
        split_bf(g, hi, lo);
        Hh[(quad * 4 + r) * 264 + n] = hi;
        Hl[(quad * 4 + r) * 264 + n] = lo;
      }
    }
  }
  __syncthreads();
  // head G2: 256 -> 64, gelu -> xl (reused as h2s)
  {
    const unsigned short* Bh = arena + OFF_WH2;
    const unsigned short* Bl = Bh + 16384;
    int n = w * 16 + lq;
    float bb = bh2[n];
    floatx4 C = {bb, bb, bb, bb};
    C = mfma_tile<256, 264>(Hh, Hl, Bh + w * 16 * 256, Bl + w * 16 * 256,
                            lq, quad, C);
    __syncthreads();
#pragma unroll
    for (int r = 0; r < 4; ++r)
      xl[(quad * 4 + r) * 64 + n] = gelu_tanh(C[r]);
  }
  __syncthreads();
  // head G3: dot with Wh3
  float wv3 = Wh3[lane];
#pragma unroll
  for (int tk = 0; tk < 4; ++tk) {
    int tok = w * 4 + tk;
    float v = xl[tok * 64 + lane] * wv3;
    float sum = wave_reduce_sum(v);
    if (lane == 0) out[tok0 + tok] = sum + bh3[0];
  }
}

// ---------------------------------------------------------------------------
extern "C" void kernel_launch(void* const* d_in, const int* in_sizes, int n_in,
                              void* d_out, int out_size, void* d_ws, size_t ws_size,
                              hipStream_t stream) {
  const float* z      = (const float*)d_in[0];
  const float* cond   = (const float*)d_in[1];
  const float* s      = (const float*)d_in[2];
  const float* embed  = (const float*)d_in[3];
  const float* Win1   = (const float*)d_in[4];
  const float* bin1   = (const float*)d_in[5];
  const float* Win2   = (const float*)d_in[6];
  const float* bin2   = (const float*)d_in[7];
  const float* ln1_s  = (const float*)d_in[8];
  const float* ln1_b  = (const float*)d_in[9];
  const float* ln2_s  = (const float*)d_in[10];
  const float* ln2_b  = (const float*)d_in[11];
  const float* Wq     = (const float*)d_in[12];
  const float* bq     = (const float*)d_in[13];
  const float* Wk     = (const float*)d_in[14];
  const float* bk     = (const float*)d_in[15];
  const float* Wv     = (const float*)d_in[16];
  const float* bv     = (const float*)d_in[17];
  const float* Wo     = (const float*)d_in[18];
  const float* bo     = (const float*)d_in[19];
  const float* rbf_c  = (const float*)d_in[20];
  const float* rbf_lw = (const float*)d_in[21];
  const float* rbf_w  = (const float*)d_in[22];
  const float* rbf_b  = (const float*)d_in[23];
  const float* W1     = (const float*)d_in[24];
  const float* b1     = (const float*)d_in[25];
  const float* W2     = (const float*)d_in[26];
  const float* b2     = (const float*)d_in[27];
  const float* Wh1    = (const float*)d_in[28];
  const float* bh1    = (const float*)d_in[29];
  const float* Wh2    = (const float*)d_in[30];
  const float* bh2    = (const float*)d_in[31];
  const float* Wh3    = (const float*)d_in[32];
  const float* bh3    = (const float*)d_in[33];

  char* base = (char*)d_ws;
  float*          x     = (float*)(base);                          // 2 MB
  unsigned short* qb    = (unsigned short*)(base + (2u << 20));    // 2 MB
  unsigned short* kb    = (unsigned short*)(base + (4u << 20));    // 2 MB
  unsigned short* vbT   = (unsigned short*)(base + (6u << 20));    // 2 MB
  float*          ob    = (float*)(base + (8u << 20));             // 4 MB
  unsigned short* biasT = (unsigned short*)(base + (12u << 20));   // 2 x 16 MB
  unsigned short* arena = (unsigned short*)(base + (48u << 20));   // ~832 KB

  PrepArgs pa;
  auto set = [&](int i, const float* sp, int K, int N, int dst) {
    pa.src[i] = sp; pa.Kd[i] = K; pa.Nd[i] = N; pa.dst[i] = dst;
    pa.elems[i] = K * N;
  };
  set(0, Win1, 128, 256, OFF_WIN1);
  set(1, Win2, 256, 64, OFF_WIN2);
  for (int lay = 0; lay < 2; ++lay) {
    int lb = OFF_LAY0 + lay * LAY_STRIDE;
    set(2 + lay * 6, Wq + lay * 8192, 64, 128, lb + OFF_WQ);
    set(3 + lay * 6, Wk + lay * 8192, 64, 128, lb + OFF_WK);
    set(4 + lay * 6, Wv + lay * 8192, 64, 128, lb + OFF_WV);
    set(5 + lay * 6, Wo + lay * 8192, 128, 64, lb + OFF_WO);
    set(6 + lay * 6, W1 + lay * 16384, 64, 256, lb + OFF_W1);
    set(7 + lay * 6, W2 + lay * 16384, 256, 64, lb + OFF_W2);
  }
  set(14, Wh1, 64, 256, OFF_WH1);
  set(15, Wh2, 256, 64, OFF_WH2);

  k_prep_bias<<<2048 + 8192, 256, 0, stream>>>(pa, arena, s, rbf_c, rbf_lw,
                                               rbf_w, rbf_b, biasT);
  k_in_qkv<<<512, 256, 0, stream>>>(embed, z, cond, arena, bin1, bin2, x,
                                    ln1_s, ln1_b, bq, bk, bv, qb, kb, vbT);
  k_attn<<<1024, 256, 0, stream>>>(qb, kb, vbT, biasT, ob);
  k_pf_qkv<<<512, 256, 0, stream>>>(ob, arena, bo, x, ln2_s, ln2_b, b1, b2, 0,
                                    ln1_s, ln1_b, bq, bk, bv, qb, kb, vbT);
  k_attn<<<1024, 256, 0, stream>>>(qb, kb, vbT,
                                   biasT + (size_t)8 * 1024 * 1024, ob);
  k_pf_head<<<512, 256, 0, stream>>>(ob, arena, bo, x, ln2_s, ln2_b, b1, b2, 1,
                                     bh1, bh2, Wh3, bh3, (float*)d_out);
}

// Round 14
// 265.412 us; speedup vs baseline: 1.0753x; 1.0074x over previous
//
#include <hip/hip_runtime.h>
#include <hip/hip_bf16.h>

// Problem constants (reference: B=8, L=1024, C=4, D=64, H=8, NB=2, K=16)
#define BB   8
#define LL   1024
#define DD   64
#define D2   128
#define D4   256
#define HH   8
#define DH   16

typedef __attribute__((ext_vector_type(8))) short short8;   // 8 bf16 (4 VGPRs)
typedef __attribute__((ext_vector_type(4))) float floatx4;  // MFMA C/D

#define LOG2E 1.4426950408889634f
// exponent offset -24 folded into the QK^T accumulator: -24/(0.25*LOG2E)
#define QK_SEED -66.54214054f

// bf16 split-weight arena offsets (elements)
#define OFF_WIN1   0        // [256][128] hi, lo at +32768
#define OFF_WIN2   65536    // [64][256]  hi, lo at +16384
#define OFF_LAY0   98304
#define LAY_STRIDE 131072
#define OFF_WQ     0        // [128][64] hi, lo +8192
#define OFF_WK     16384
#define OFF_WV     32768
#define OFF_WO     49152    // [64][128] hi, lo +8192
#define OFF_W1     65536    // [256][64] hi, lo +16384
#define OFF_W2     98304    // [64][256] hi, lo +16384
#define OFF_WH1    360448   // [256][64] hi, lo +16384
#define OFF_WH2    393216   // [64][256] hi, lo +16384

__device__ __forceinline__ float gelu_tanh(float u) {
  float t = tanhf(0.7978845608028654f * (u + 0.044715f * u * u * u));
  return 0.5f * u * (1.0f + t);
}

__device__ __forceinline__ float wave_reduce_sum(float v) {
#pragma unroll
  for (int m = 32; m >= 1; m >>= 1) v += __shfl_xor(v, m, 64);
  return v;
}

__device__ __forceinline__ unsigned short f2bf(float x) {  // RNE
  unsigned u = __float_as_uint(x);
  u += 0x7fffu + ((u >> 16) & 1u);
  return (unsigned short)(u >> 16);
}

__device__ __forceinline__ float bf2f(unsigned short x) {
  return __uint_as_float(((unsigned)x) << 16);
}

__device__ __forceinline__ void split_bf(float v, unsigned short& hi,
                                         unsigned short& lo) {
  hi = f2bf(v);
  lo = f2bf(v - bf2f(hi));
}

// pack two fp32 -> two bf16 (round-half-up) in one v_perm_b32
__device__ __forceinline__ unsigned pack_bf2(float a, float b) {
  unsigned ua = __float_as_uint(a) + 0x8000u;
  unsigned ub = __float_as_uint(b) + 0x8000u;
  return __builtin_amdgcn_perm(ub, ua, 0x07060302u);  // (bf(b)<<16)|bf(a)
}

// 16x16 output tile over K with 3-term bf16 split (single accumulator).
template <int K, int KP>
__device__ __forceinline__ floatx4 mfma_tile(
    const unsigned short* Ah, const unsigned short* Al,
    const unsigned short* __restrict__ Bh, const unsigned short* __restrict__ Bl,
    int lq, int quad, floatx4 C) {
#pragma unroll
  for (int kk = 0; kk < K; kk += 32) {
    short8 ah = *(const short8*)(Ah + lq * KP + kk + quad * 8);
    short8 al = *(const short8*)(Al + lq * KP + kk + quad * 8);
    short8 bh = *(const short8*)(Bh + lq * K + kk + quad * 8);
    short8 bl = *(const short8*)(Bl + lq * K + kk + quad * 8);
    C = __builtin_amdgcn_mfma_f32_16x16x32_bf16(ah, bh, C, 0, 0, 0);
    C = __builtin_amdgcn_mfma_f32_16x16x32_bf16(al, bh, C, 0, 0, 0);
    C = __builtin_amdgcn_mfma_f32_16x16x32_bf16(ah, bl, C, 0, 0, 0);
  }
  return C;
}

// ---------------------------------------------------------------------------
// K0: merged weight prep (bid<2048) + RBF bias (rest). Flat grid.
// bias stored PRE-SCALED by log2(e) so attn softmax runs in exp2 domain.
// ---------------------------------------------------------------------------
struct PrepArgs {
  const float* src[16];
  int Kd[16], Nd[16], dst[16], elems[16];
};

__global__ __launch_bounds__(256) void k_prep_bias(
    PrepArgs a, unsigned short* __restrict__ arena,
    const float* __restrict__ s, const float* __restrict__ rbf_c,
    const float* __restrict__ rbf_logw, const float* __restrict__ rbf_w,
    const float* __restrict__ rbf_b, unsigned short* __restrict__ biasT) {
  int bid = blockIdx.x, t = threadIdx.x;
  if (bid < 2048) {
    int mid = bid >> 7;
    int e = (bid & 127) * 256 + t;
    int KN = a.elems[mid];
    if (e >= KN) return;
    int K = a.Kd[mid], N = a.Nd[mid];
    int n = e / K, k = e - n * K;
    float wv = a.src[mid][k * N + n];
    unsigned short hi, lo;
    split_bf(wv, hi, lo);
    arena[a.dst[mid] + e] = hi;
    arena[a.dst[mid] + KN + e] = lo;
    return;
  }
  int rem = bid - 2048;
  int lay = rem >> 12;
  int id = (rem & 4095) * 256 + t;
  int q = id >> 10, k = id & 1023;
  float dd = s[q] - s[k];  // dist[q,k] = s[q]-s[k]
  float acc[8];
#pragma unroll
  for (int h = 0; h < 8; ++h) acc[h] = rbf_b[lay * 8 + h];
#pragma unroll 1
  for (int f = 0; f < 16; ++f) {
    float c = rbf_c[lay * 16 + f];
    float inv2w2 = 0.5f * __expf(-2.0f * rbf_logw[lay * 16 + f]);
    float e = dd - c;
    float ph = __expf(-e * e * inv2w2);
#pragma unroll
    for (int h = 0; h < 8; ++h)
      acc[h] = fmaf(ph, rbf_w[lay * 128 + f * 8 + h], acc[h]);
  }
  unsigned short* bT = biasT + (size_t)lay * 8 * 1024 * 1024;
#pragma unroll
  for (int h = 0; h < 8; ++h)
    bT[(size_t)(h * 1024 + q) * 1024 + k] = f2bf(acc[h] * LOG2E);
}

// Shared QKV tail: LN(xl) -> split -> 3 MFMA mats -> q/k global, v transposed.
__device__ __forceinline__ void qkv_tail(
    const float* xl, unsigned short* Sh, unsigned short* Sl,
    const unsigned short* __restrict__ arena, int lay,
    const float* __restrict__ ln_s, const float* __restrict__ ln_b,
    const float* __restrict__ bq, const float* __restrict__ bk,
    const float* __restrict__ bv, unsigned short* __restrict__ qo,
    unsigned short* __restrict__ ko, unsigned short* __restrict__ voT,
    int tok0, int t) {
  int w = t >> 6, lane = t & 63;
  int lq = lane & 15, quad = lane >> 4;
  float ss = ln_s[lay * 64 + lane], sb = ln_b[lay * 64 + lane];
#pragma unroll
  for (int tk = 0; tk < 4; ++tk) {
    int tok = w * 4 + tk;
    float v = xl[tok * 64 + lane];
    float mean = wave_reduce_sum(v) * 0.015625f;
    float d = v - mean;
    float var = wave_reduce_sum(d * d) * 0.015625f;
    float hv = d * rsqrtf(var + 1e-6f) * ss + sb;
    unsigned short hi, lo;
    split_bf(hv, hi, lo);
    Sh[tok * 72 + lane] = hi;
    Sl[tok * 72 + lane] = lo;
  }
  __syncthreads();
  int b = tok0 >> 10, l0 = tok0 & 1023;
#pragma unroll 1
  for (int mat = 0; mat < 3; ++mat) {
    const unsigned short* Bh =
        arena + OFF_LAY0 + lay * LAY_STRIDE + mat * 16384;
    const unsigned short* Bl = Bh + 8192;
    const float* bias = (mat == 0 ? bq : mat == 1 ? bk : bv) + lay * 128;
#pragma unroll
    for (int j = 0; j < 2; ++j) {
      int tl = w + j * 4;  // head index
      int n = tl * 16 + lq;
      float bb = bias[n];
      floatx4 C = {bb, bb, bb, bb};
      C = mfma_tile<64, 72>(Sh, Sl, Bh + tl * 16 * 64, Bl + tl * 16 * 64,
                            lq, quad, C);
      if (mat < 2) {
        unsigned short* outp = (mat == 0 ? qo : ko);
        size_t basea = ((size_t)(b * 8 + tl) * 1024 + l0 + quad * 4) * 16 + lq;
#pragma unroll
        for (int r = 0; r < 4; ++r)
          outp[basea + (size_t)r * 16] = f2bf(C[r]);
      } else {
        size_t basev = ((size_t)(b * 8 + tl) * 16 + lq) * 1024 + l0 + quad * 4;
#pragma unroll
        for (int r = 0; r < 4; ++r)
          voT[basev + r] = f2bf(C[r]);
      }
    }
  }
}

// ---------------------------------------------------------------------------
// K1: input MLP + LN1 + QKV (layer 0). 16 tokens/block.
// ---------------------------------------------------------------------------
__global__ __launch_bounds__(256) void k_in_qkv(
    const float* __restrict__ embed, const float* __restrict__ z,
    const float* __restrict__ cond, const unsigned short* __restrict__ arena,
    const float* __restrict__ bin1, const float* __restrict__ bin2,
    float* __restrict__ x, const float* __restrict__ ln1_s,
    const float* __restrict__ ln1_b, const float* __restrict__ bq,
    const float* __restrict__ bk, const float* __restrict__ bv,
    unsigned short* __restrict__ qo, unsigned short* __restrict__ ko,
    unsigned short* __restrict__ voT) {
  __shared__ __align__(16) unsigned short Ah[16 * 136], Al[16 * 136];
  __shared__ __align__(16) unsigned short Hh[16 * 264], Hl[16 * 264];
  __shared__ __align__(16) unsigned short Sh[16 * 72], Sl[16 * 72];
  __shared__ float xl[16 * 64];
  int t = threadIdx.x, w = t >> 6, lane = t & 63;
  int lq = lane & 15, quad = lane >> 4;
  int tok0 = blockIdx.x * 16;
  for (int idx = t; idx < 2048; idx += 256) {
    int tok = idx >> 7, dim = idx & 127;
    int bl = tok0 + tok, l = bl & (LL - 1);
    float v;
    if (dim < 123) v = embed[l * 123 + dim];
    else if (dim == 123) v = z[bl];
    else v = cond[dim - 124];
    unsigned short hi, lo;
    split_bf(v, hi, lo);
    Ah[tok * 136 + dim] = hi;
    Al[tok * 136 + dim] = lo;
  }
  __syncthreads();
  // G1: 128 -> 256, gelu
  const unsigned short* B1h = arena + OFF_WIN1;
  const unsigned short* B1l = B1h + 32768;
#pragma unroll
  for (int j = 0; j < 4; ++j) {
    int tl = w * 4 + j, n = tl * 16 + lq;
    float bb = bin1[n];
    floatx4 C = {bb, bb, bb, bb};
    C = mfma_tile<128, 136>(Ah, Al, B1h + tl * 16 * 128, B1l + tl * 16 * 128,
                            lq, quad, C);
#pragma unroll
    for (int r = 0; r < 4; ++r) {
      float g = gelu_tanh(C[r]);
      unsigned short hi, lo;
      split_bf(g, hi, lo);
      Hh[(quad * 4 + r) * 264 + n] = hi;
      Hl[(quad * 4 + r) * 264 + n] = lo;
    }
  }
  __syncthreads();
  // G2: 256 -> 64 -> x (global + xl)
  const unsigned short* B2h = arena + OFF_WIN2;
  const unsigned short* B2l = B2h + 16384;
  {
    int n = w * 16 + lq;
    float bb = bin2[n];
    floatx4 C = {bb, bb, bb, bb};
    C = mfma_tile<256, 264>(Hh, Hl, B2h + w * 16 * 256, B2l + w * 16 * 256,
                            lq, quad, C);
#pragma unroll
    for (int r = 0; r < 4; ++r) {
      int m = quad * 4 + r;
      x[(size_t)(tok0 + m) * 64 + n] = C[r];
      xl[m * 64 + n] = C[r];
    }
  }
  __syncthreads();
  qkv_tail(xl, Sh, Sl, arena, 0, ln1_s, ln1_b, bq, bk, bv,
           qo, ko, voT, tok0, t);
}

// ---------------------------------------------------------------------------
// K4: MFMA flash attention (r11 single-buffer config — the double-buffer
// variant failed the post-timing determinism tripwire in r13; reverted).
// No-max softmax, exp2 domain. 64 q/block, 1024 blocks.
// bias [h][q][k] pre-scaled by log2e; V pre-transposed [bh][d][l].
// ---------------------------------------------------------------------------
__global__ __launch_bounds__(256) void k_attn(
    const unsigned short* __restrict__ qg, const unsigned short* __restrict__ kg,
    const unsigned short* __restrict__ vgT, const unsigned short* __restrict__ biasT,
    float* __restrict__ og) {
  __shared__ __align__(16) unsigned short Kl[64 * 32];     // 4 KB
  __shared__ __align__(16) unsigned short VT[16 * 72];     // 2.25 KB
  __shared__ __align__(16) unsigned short Pl[4][16 * 72];  // 9 KB
  __shared__ __align__(16) unsigned short Bch[64 * 72];    // 9 KB [q][k]
  int t = threadIdx.x, w = t >> 6, lane = t & 63;
  int lq = lane & 15, quad = lane >> 4;
  int bid = blockIdx.x;
  int b = bid >> 7, h = (bid >> 4) & 7, qblk = bid & 15;
  int q0w = qblk * 64 + w * 16;
  size_t bh = (size_t)(b * 8 + h) * 1024;
  size_t bh16 = (size_t)(b * 8 + h) * 16;

  ((uint4*)Kl)[t] = uint4{0, 0, 0, 0};  // zero d16..31 pad

  short8 Qb = {};
  if (quad < 2)
    Qb = *(const short8*)(qg + (bh + q0w + lq) * 16 + quad * 8);

  float l = 0.0f;
  floatx4 O = {0.0f, 0.0f, 0.0f, 0.0f};

  // staging assignments (all vectorized)
  int key = t >> 2, dp = (t & 3) * 4;        // K: 1 uint2 / thread
  int drow = t >> 4, vcol = (t & 15) * 4;    // V^T: 1 uint2 / thread
  int qrow = t >> 2, bcol = (t & 3) * 16;    // bias: 2 uint4 / thread (16 ush)
  const unsigned short* kgp = kg + (bh + key) * 16 + dp;
  const unsigned short* vgp = vgT + (bh16 + drow) * 1024 + vcol;
  const unsigned short* bgp =
      biasT + ((size_t)(h * 1024 + qblk * 64 + qrow)) * 1024 + bcol;

  uint2 kpre = *(const uint2*)(kgp);
  uint2 vpre = *(const uint2*)(vgp);
  uint4 bpre0 = *(const uint4*)(bgp);
  uint4 bpre1 = *(const uint4*)(bgp + 8);

#pragma unroll 1
  for (int kc = 0; kc < 1024; kc += 64) {
    __syncthreads();
    *(uint2*)(Kl + key * 32 + dp) = kpre;
    *(uint2*)(VT + drow * 72 + vcol) = vpre;
    *(uint4*)(Bch + qrow * 72 + bcol) = bpre0;
    *(uint4*)(Bch + qrow * 72 + bcol + 8) = bpre1;
    __syncthreads();
    if (kc + 64 < 1024) {
      kpre = *(const uint2*)(kgp + (size_t)(kc + 64) * 16);
      vpre = *(const uint2*)(vgp + (kc + 64));
      bpre0 = *(const uint4*)(bgp + (kc + 64));
      bpre1 = *(const uint4*)(bgp + (kc + 64) + 8);
    }
    // QK^T + bias -> p = exp2(s) directly (offset is in the seed)
    float psum = 0.0f;
    unsigned short* pw = &Pl[w][lq * 72];
#pragma unroll
    for (int tile = 0; tile < 4; ++tile) {
      short8 A = *(const short8*)(Kl + (tile * 16 + lq) * 32 + quad * 8);
      floatx4 c = {QK_SEED, QK_SEED, QK_SEED, QK_SEED};
      c = __builtin_amdgcn_mfma_f32_16x16x32_bf16(A, Qb, c, 0, 0, 0);
      ushort4 bb = *(const ushort4*)(Bch + (w * 16 + lq) * 72 +
                                     tile * 16 + quad * 4);
      float p0 = exp2f(fmaf(c[0], 0.25f * LOG2E, bf2f(bb.x)));
      float p1 = exp2f(fmaf(c[1], 0.25f * LOG2E, bf2f(bb.y)));
      float p2 = exp2f(fmaf(c[2], 0.25f * LOG2E, bf2f(bb.z)));
      float p3 = exp2f(fmaf(c[3], 0.25f * LOG2E, bf2f(bb.w)));
      psum += (p0 + p1) + (p2 + p3);
      uint2 pk;
      pk.x = pack_bf2(p0, p1);
      pk.y = pack_bf2(p2, p3);
      *(uint2*)(pw + tile * 16 + quad * 4) = pk;
    }
    psum += __shfl_xor(psum, 16, 64);
    psum += __shfl_xor(psum, 32, 64);
    l += psum;
    asm volatile("s_waitcnt lgkmcnt(0)" ::: "memory");
    // PV: 2 MFMAs (K=32 keys each), no rescale needed
#pragma unroll
    for (int i = 0; i < 2; ++i) {
      short8 Pa = *(const short8*)(pw + i * 32 + quad * 8);
      short8 Vb = *(const short8*)(&VT[lq * 72 + i * 32 + quad * 8]);
      O = __builtin_amdgcn_mfma_f32_16x16x32_bf16(Pa, Vb, O, 0, 0, 0);
    }
  }
  float linv = 1.0f / l;
#pragma unroll
  for (int r = 0; r < 4; ++r) {
    int idx = (quad * 4 + r) * 4;
    float lr = __uint_as_float(
        __builtin_amdgcn_ds_bpermute(idx, __float_as_uint(linv)));
    og[((size_t)(b * 1024 + q0w + quad * 4 + r)) * 128 + h * 16 + lq] = O[r] * lr;
  }
}

// Shared proj+LN2+FFN body. Returns with xl holding the post-FFN x rows.
__device__ __forceinline__ void pf_body(
    const float* __restrict__ ob, const unsigned short* __restrict__ arena,
    const float* __restrict__ bo, float* __restrict__ x,
    const float* __restrict__ ln_s, const float* __restrict__ ln_b,
    const float* __restrict__ b1, const float* __restrict__ b2, int lay,
    unsigned short* Ah, unsigned short* Al, unsigned short* Sh,
    unsigned short* Sl, unsigned short* Hh, unsigned short* Hl, float* xl,
    int tok0, int t, bool write_x) {
  int w = t >> 6, lane = t & 63;
  int lq = lane & 15, quad = lane >> 4;
  const unsigned short* labase = arena + OFF_LAY0 + lay * LAY_STRIDE;
  // stage attn-o split
  for (int idx = t * 4; idx < 2048; idx += 1024) {
    int row = idx >> 7, col = idx & 127;
    float4 v = *(const float4*)(ob + (size_t)(tok0 + row) * 128 + col);
    unsigned short h0, e0, h1, e1, h2, e2, h3, e3;
    split_bf(v.x, h0, e0); split_bf(v.y, h1, e1);
    split_bf(v.z, h2, e2); split_bf(v.w, h3, e3);
    unsigned* ph = (unsigned*)(Ah + row * 136 + col);
    ph[0] = (unsigned)h0 | ((unsigned)h1 << 16);
    ph[1] = (unsigned)h2 | ((unsigned)h3 << 16);
    unsigned* pl = (unsigned*)(Al + row * 136 + col);
    pl[0] = (unsigned)e0 | ((unsigned)e1 << 16);
    pl[1] = (unsigned)e2 | ((unsigned)e3 << 16);
  }
  __syncthreads();
  // proj: 128 -> 64, + residual -> xl
  {
    const unsigned short* Bh = labase + OFF_WO;
    const unsigned short* Bl = Bh + 8192;
    int n = w * 16 + lq;
    float bb = bo[lay * 64 + n];
    floatx4 C = {bb, bb, bb, bb};
    C = mfma_tile<128, 136>(Ah, Al, Bh + w * 16 * 128, Bl + w * 16 * 128,
                            lq, quad, C);
#pragma unroll
    for (int r = 0; r < 4; ++r) {
      int m = quad * 4 + r;
      xl[m * 64 + n] = x[(size_t)(tok0 + m) * 64 + n] + C[r];
    }
  }
  __syncthreads();
  // LN2 -> Sh/Sl
  {
    float ss = ln_s[lay * 64 + lane], sb = ln_b[lay * 64 + lane];
#pragma unroll
    for (int tk = 0; tk < 4; ++tk) {
      int tok = w * 4 + tk;
      float v = xl[tok * 64 + lane];
      float mean = wave_reduce_sum(v) * 0.015625f;
      float d = v - mean;
      float var = wave_reduce_sum(d * d) * 0.015625f;
      float hv = d * rsqrtf(var + 1e-6f) * ss + sb;
      unsigned short hi, lo;
      split_bf(hv, hi, lo);
      Sh[tok * 72 + lane] = hi;
      Sl[tok * 72 + lane] = lo;
    }
  }
  __syncthreads();
  // FFN G1: 64 -> 256, gelu
  {
    const unsigned short* Bh = labase + OFF_W1;
    const unsigned short* Bl = Bh + 16384;
#pragma unroll
    for (int j = 0; j < 4; ++j) {
      int tl = w * 4 + j, n = tl * 16 + lq;
      float bb = b1[lay * 256 + n];
      floatx4 C = {bb, bb, bb, bb};
      C = mfma_tile<64, 72>(Sh, Sl, Bh + tl * 16 * 64, Bl + tl * 16 * 64,
                            lq, quad, C);
#pragma unroll
      for (int r = 0; r < 4; ++r) {
        float g = gelu_tanh(C[r]);
        unsigned short hi, lo;
        split_bf(g, hi, lo);
        Hh[(quad * 4 + r) * 264 + n] = hi;
        Hl[(quad * 4 + r) * 264 + n] = lo;
      }
    }
  }
  __syncthreads();
  // FFN G2: 256 -> 64, + residual -> xl (and optionally x)
  {
    const unsigned short* Bh = labase + OFF_W2;
    const unsigned short* Bl = Bh + 16384;
    int n = w * 16 + lq;
    float bb = b2[lay * 64 + n];
    floatx4 C = {bb, bb, bb, bb};
    C = mfma_tile<256, 264>(Hh, Hl, Bh + w * 16 * 256, Bl + w * 16 * 256,
                            lq, quad, C);
#pragma unroll
    for (int r = 0; r < 4; ++r) {
      int m = quad * 4 + r;
      float xv = xl[m * 64 + n] + C[r];
      xl[m * 64 + n] = xv;
      if (write_x) x[(size_t)(tok0 + m) * 64 + n] = xv;
    }
  }
  __syncthreads();
}

// ---------------------------------------------------------------------------
// K5a: proj+LN2+FFN (layer lay) then LN1+QKV (layer lay+1).
// ---------------------------------------------------------------------------
__global__ __launch_bounds__(256) void k_pf_qkv(
    const float* __restrict__ ob, const unsigned short* __restrict__ arena,
    const float* __restrict__ bo, float* __restrict__ x,
    const float* __restrict__ ln2_s, const float* __restrict__ ln2_b,
    const float* __restrict__ b1, const float* __restrict__ b2, int lay,
    const float* __restrict__ ln1_s, const float* __restrict__ ln1_b,
    const float* __restrict__ bq, const float* __restrict__ bk,
    const float* __restrict__ bv, unsigned short* __restrict__ qo,
    unsigned short* __restrict__ ko, unsigned short* __restrict__ voT) {
  __shared__ __align__(16) unsigned short Ah[16 * 136], Al[16 * 136];
  __shared__ __align__(16) unsigned short Sh[16 * 72], Sl[16 * 72];
  __shared__ __align__(16) unsigned short Hh[16 * 264], Hl[16 * 264];
  __shared__ float xl[16 * 64];
  int t = threadIdx.x;
  int tok0 = blockIdx.x * 16;
  pf_body(ob, arena, bo, x, ln2_s, ln2_b, b1, b2, lay,
          Ah, Al, Sh, Sl, Hh, Hl, xl, tok0, t, true);
  qkv_tail(xl, Sh, Sl, arena, lay + 1, ln1_s, ln1_b, bq, bk, bv,
           qo, ko, voT, tok0, t);
}

// ---------------------------------------------------------------------------
// K5b: proj+LN2+FFN (last layer) then head MLP.
// ---------------------------------------------------------------------------
__global__ __launch_bounds__(256) void k_pf_head(
    const float* __restrict__ ob, const unsigned short* __restrict__ arena,
    const float* __restrict__ bo, float* __restrict__ x,
    const float* __restrict__ ln2_s, const float* __restrict__ ln2_b,
    const float* __restrict__ b1, const float* __restrict__ b2, int lay,
    const float* __restrict__ bh1, const float* __restrict__ bh2,
    const float* __restrict__ Wh3, const float* __restrict__ bh3,
    float* __restrict__ out) {
  __shared__ __align__(16) unsigned short Ah[16 * 136], Al[16 * 136];
  __shared__ __align__(16) unsigned short Sh[16 * 72], Sl[16 * 72];
  __shared__ __align__(16) unsigned short Hh[16 * 264], Hl[16 * 264];
  __shared__ float xl[16 * 64];
  int t = threadIdx.x, w = t >> 6, lane = t & 63;
  int lq = lane & 15, quad = lane >> 4;
  int tok0 = blockIdx.x * 16;
  pf_body(ob, arena, bo, x, ln2_s, ln2_b, b1, b2, lay,
          Ah, Al, Sh, Sl, Hh, Hl, xl, tok0, t, false);
  // split raw x -> Sh/Sl
#pragma unroll
  for (int tk = 0; tk < 4; ++tk) {
    int tok = w * 4 + tk;
    unsigned short hi, lo;
    split_bf(xl[tok * 64 + lane], hi, lo);
    Sh[tok * 72 + lane] = hi;
    Sl[tok * 72 + lane] = lo;
  }
  __syncthreads();
  // head G1: 64 -> 256, gelu
  {
    const unsigned short* Bh = arena + OFF_WH1;
    const unsigned short* Bl = Bh + 16384;
#pragma unroll
    for (int j = 0; j < 4; ++j) {
      int tl = w * 4 + j, n = tl * 16 + lq;
      float bb = bh1[n];
      floatx4 C = {bb, bb, bb, bb};
      C = mfma_tile<64, 72>(Sh, Sl, Bh + tl * 16 * 64, Bl + tl * 16 * 64,
                            lq, quad, C);
#pragma unroll
      for (int r = 0; r < 4; ++r) {
        float g = gelu_tanh(C[r]);
        unsigned short hi, lo;
        split_bf(g, hi, lo);
        Hh[(quad * 4 + r) * 264 + n] = hi;
        Hl[(quad * 4 + r) * 264 + n] = lo;
      }
    }
  }
  __syncthreads();
  // head G2: 256 -> 64, gelu -> xl (reused as h2s)
  {
    const unsigned short* Bh = arena + OFF_WH2;
    const unsigned short* Bl = Bh + 16384;
    int n = w * 16 + lq;
    float bb = bh2[n];
    floatx4 C = {bb, bb, bb, bb};
    C = mfma_tile<256, 264>(Hh, Hl, Bh + w * 16 * 256, Bl + w * 16 * 256,
                            lq, quad, C);
    __syncthreads();
#pragma unroll
    for (int r = 0; r < 4; ++r)
      xl[(quad * 4 + r) * 64 + n] = gelu_tanh(C[r]);
  }
  __syncthreads();
  // head G3: dot with Wh3
  float wv3 = Wh3[lane];
#pragma unroll
  for (int tk = 0; tk < 4; ++tk) {
    int tok = w * 4 + tk;
    float v = xl[tok * 64 + lane] * wv3;
    float sum = wave_reduce_sum(v);
    if (lane == 0) out[tok0 + tok] = sum + bh3[0];
  }
}

// ---------------------------------------------------------------------------
extern "C" void kernel_launch(void* const* d_in, const int* in_sizes, int n_in,
                              void* d_out, int out_size, void* d_ws, size_t ws_size,
                              hipStream_t stream) {
  const float* z      = (const float*)d_in[0];
  const float* cond   = (const float*)d_in[1];
  const float* s      = (const float*)d_in[2];
  const float* embed  = (const float*)d_in[3];
  const float* Win1   = (const float*)d_in[4];
  const float* bin1   = (const float*)d_in[5];
  const float* Win2   = (const float*)d_in[6];
  const float* bin2   = (const float*)d_in[7];
  const float* ln1_s  = (const float*)d_in[8];
  const float* ln1_b  = (const float*)d_in[9];
  const float* ln2_s  = (const float*)d_in[10];
  const float* ln2_b  = (const float*)d_in[11];
  const float* Wq     = (const float*)d_in[12];
  const float* bq     = (const float*)d_in[13];
  const float* Wk     = (const float*)d_in[14];
  const float* bk     = (const float*)d_in[15];
  const float* Wv     = (const float*)d_in[16];
  const float* bv     = (const float*)d_in[17];
  const float* Wo     = (const float*)d_in[18];
  const float* bo     = (const float*)d_in[19];
  const float* rbf_c  = (const float*)d_in[20];
  const float* rbf_lw = (const float*)d_in[21];
  const float* rbf_w  = (const float*)d_in[22];
  const float* rbf_b  = (const float*)d_in[23];
  const float* W1     = (const float*)d_in[24];
  const float* b1     = (const float*)d_in[25];
  const float* W2     = (const float*)d_in[26];
  const float* b2     = (const float*)d_in[27];
  const float* Wh1    = (const float*)d_in[28];
  const float* bh1    = (const float*)d_in[29];
  const float* Wh2    = (const float*)d_in[30];
  const float* bh2    = (const float*)d_in[31];
  const float* Wh3    = (const float*)d_in[32];
  const float* bh3    = (const float*)d_in[33];

  char* base = (char*)d_ws;
  float*          x     = (float*)(base);                          // 2 MB
  unsigned short* qb    = (unsigned short*)(base + (2u << 20));    // 2 MB
  unsigned short* kb    = (unsigned short*)(base + (4u << 20));    // 2 MB
  unsigned short* vbT   = (unsigned short*)(base + (6u << 20));    // 2 MB
  float*          ob    = (float*)(base + (8u << 20));             // 4 MB
  unsigned short* biasT = (unsigned short*)(base + (12u << 20));   // 2 x 16 MB
  unsigned short* arena = (unsigned short*)(base + (48u << 20));   // ~832 KB

  PrepArgs pa;
  auto set = [&](int i, const float* sp, int K, int N, int dst) {
    pa.src[i] = sp; pa.Kd[i] = K; pa.Nd[i] = N; pa.dst[i] = dst;
    pa.elems[i] = K * N;
  };
  set(0, Win1, 128, 256, OFF_WIN1);
  set(1, Win2, 256, 64, OFF_WIN2);
  for (int lay = 0; lay < 2; ++lay) {
    int lb = OFF_LAY0 + lay * LAY_STRIDE;
    set(2 + lay * 6, Wq + lay * 8192, 64, 128, lb + OFF_WQ);
    set(3 + lay * 6, Wk + lay * 8192, 64, 128, lb + OFF_WK);
    set(4 + lay * 6, Wv + lay * 8192, 64, 128, lb + OFF_WV);
    set(5 + lay * 6, Wo + lay * 8192, 128, 64, lb + OFF_WO);
    set(6 + lay * 6, W1 + lay * 16384, 64, 256, lb + OFF_W1);
    set(7 + lay * 6, W2 + lay * 16384, 256, 64, lb + OFF_W2);
  }
  set(14, Wh1, 64, 256, OFF_WH1);
  set(15, Wh2, 256, 64, OFF_WH2);

  k_prep_bias<<<2048 + 8192, 256, 0, stream>>>(pa, arena, s, rbf_c, rbf_lw,
                                               rbf_w, rbf_b, biasT);
  k_in_qkv<<<512, 256, 0, stream>>>(embed, z, cond, arena, bin1, bin2, x,
                                    ln1_s, ln1_b, bq, bk, bv, qb, kb, vbT);
  k_attn<<<1024, 256, 0, stream>>>(qb, kb, vbT, biasT, ob);
  k_pf_qkv<<<512, 256, 0, stream>>>(ob, arena, bo, x, ln2_s, ln2_b, b1, b2, 0,
                                    ln1_s, ln1_b, bq, bk, bv, qb, kb, vbT);
  k_attn<<<1024, 256, 0, stream>>>(qb, kb, vbT,
                                   biasT + (size_t)8 * 1024 * 1024, ob);
  k_pf_head<<<512, 256, 0, stream>>>(ob, arena, bo, x, ln2_s, ln2_b, b1, b2, 1,
                                     bh1, bh2, Wh3, bh3, (float*)d_out);
}

// Round 15
// 264.621 us; speedup vs baseline: 1.0786x; 1.0030x over previous
//
#include <hip/hip_runtime.h>
#include <hip/hip_bf16.h>

// Problem constants (reference: B=8, L=1024, C=4, D=64, H=8, NB=2, K=16)
#define BB   8
#define LL   1024
#define DD   64
#define D2   128
#define D4   256
#define HH   8
#define DH   16

typedef __attribute__((ext_vector_type(8))) short short8;   // 8 bf16 (4 VGPRs)
typedef __attribute__((ext_vector_type(4))) float floatx4;  // MFMA C/D

#define LOG2E 1.4426950408889634f
// exponent offset -24 folded into the QK^T accumulator: -24/(0.25*LOG2E)
#define QK_SEED -66.54214054f

#define OB_HALF 1048576   // 8192*128 floats per attn partial half
#define L_HALF  65536     // 8192*8 floats per half

// bf16 split-weight arena offsets (elements)
#define OFF_WIN1   0        // [256][128] hi, lo at +32768
#define OFF_WIN2   65536    // [64][256]  hi, lo at +16384
#define OFF_LAY0   98304
#define LAY_STRIDE 131072
#define OFF_WQ     0        // [128][64] hi, lo +8192
#define OFF_WK     16384
#define OFF_WV     32768
#define OFF_WO     49152    // [64][128] hi, lo +8192
#define OFF_W1     65536    // [256][64] hi, lo +16384
#define OFF_W2     98304    // [64][256] hi, lo +16384
#define OFF_WH1    360448   // [256][64] hi, lo +16384
#define OFF_WH2    393216   // [64][256] hi, lo +16384

__device__ __forceinline__ float gelu_tanh(float u) {
  float t = tanhf(0.7978845608028654f * (u + 0.044715f * u * u * u));
  return 0.5f * u * (1.0f + t);
}

__device__ __forceinline__ float wave_reduce_sum(float v) {
#pragma unroll
  for (int m = 32; m >= 1; m >>= 1) v += __shfl_xor(v, m, 64);
  return v;
}

__device__ __forceinline__ unsigned short f2bf(float x) {  // RNE
  unsigned u = __float_as_uint(x);
  u += 0x7fffu + ((u >> 16) & 1u);
  return (unsigned short)(u >> 16);
}

__device__ __forceinline__ float bf2f(unsigned short x) {
  return __uint_as_float(((unsigned)x) << 16);
}

__device__ __forceinline__ void split_bf(float v, unsigned short& hi,
                                         unsigned short& lo) {
  hi = f2bf(v);
  lo = f2bf(v - bf2f(hi));
}

// pack two fp32 -> two bf16 (round-half-up) in one v_perm_b32
__device__ __forceinline__ unsigned pack_bf2(float a, float b) {
  unsigned ua = __float_as_uint(a) + 0x8000u;
  unsigned ub = __float_as_uint(b) + 0x8000u;
  return __builtin_amdgcn_perm(ub, ua, 0x07060302u);  // (bf(b)<<16)|bf(a)
}

// 16x16 output tile over K with 3-term bf16 split (single accumulator).
template <int K, int KP>
__device__ __forceinline__ floatx4 mfma_tile(
    const unsigned short* Ah, const unsigned short* Al,
    const unsigned short* __restrict__ Bh, const unsigned short* __restrict__ Bl,
    int lq, int quad, floatx4 C) {
#pragma unroll
  for (int kk = 0; kk < K; kk += 32) {
    short8 ah = *(const short8*)(Ah + lq * KP + kk + quad * 8);
    short8 al = *(const short8*)(Al + lq * KP + kk + quad * 8);
    short8 bh = *(const short8*)(Bh + lq * K + kk + quad * 8);
    short8 bl = *(const short8*)(Bl + lq * K + kk + quad * 8);
    C = __builtin_amdgcn_mfma_f32_16x16x32_bf16(ah, bh, C, 0, 0, 0);
    C = __builtin_amdgcn_mfma_f32_16x16x32_bf16(al, bh, C, 0, 0, 0);
    C = __builtin_amdgcn_mfma_f32_16x16x32_bf16(ah, bl, C, 0, 0, 0);
  }
  return C;
}

// ---------------------------------------------------------------------------
// K0: merged weight prep (bid<2048) + RBF bias (rest). Flat grid.
// bias stored PRE-SCALED by log2(e) so attn softmax runs in exp2 domain.
// ---------------------------------------------------------------------------
struct PrepArgs {
  const float* src[16];
  int Kd[16], Nd[16], dst[16], elems[16];
};

__global__ __launch_bounds__(256) void k_prep_bias(
    PrepArgs a, unsigned short* __restrict__ arena,
    const float* __restrict__ s, const float* __restrict__ rbf_c,
    const float* __restrict__ rbf_logw, const float* __restrict__ rbf_w,
    const float* __restrict__ rbf_b, unsigned short* __restrict__ biasT) {
  int bid = blockIdx.x, t = threadIdx.x;
  if (bid < 2048) {
    int mid = bid >> 7;
    int e = (bid & 127) * 256 + t;
    int KN = a.elems[mid];
    if (e >= KN) return;
    int K = a.Kd[mid], N = a.Nd[mid];
    int n = e / K, k = e - n * K;
    float wv = a.src[mid][k * N + n];
    unsigned short hi, lo;
    split_bf(wv, hi, lo);
    arena[a.dst[mid] + e] = hi;
    arena[a.dst[mid] + KN + e] = lo;
    return;
  }
  int rem = bid - 2048;
  int lay = rem >> 12;
  int id = (rem & 4095) * 256 + t;
  int q = id >> 10, k = id & 1023;
  float dd = s[q] - s[k];  // dist[q,k] = s[q]-s[k]
  float acc[8];
#pragma unroll
  for (int h = 0; h < 8; ++h) acc[h] = rbf_b[lay * 8 + h];
#pragma unroll 1
  for (int f = 0; f < 16; ++f) {
    float c = rbf_c[lay * 16 + f];
    float inv2w2 = 0.5f * __expf(-2.0f * rbf_logw[lay * 16 + f]);
    float e = dd - c;
    float ph = __expf(-e * e * inv2w2);
#pragma unroll
    for (int h = 0; h < 8; ++h)
      acc[h] = fmaf(ph, rbf_w[lay * 128 + f * 8 + h], acc[h]);
  }
  unsigned short* bT = biasT + (size_t)lay * 8 * 1024 * 1024;
#pragma unroll
  for (int h = 0; h < 8; ++h)
    bT[(size_t)(h * 1024 + q) * 1024 + k] = f2bf(acc[h] * LOG2E);
}

// Shared QKV tail: LN(xl) -> split -> 3 MFMA mats -> q/k global, v transposed.
__device__ __forceinline__ void qkv_tail(
    const float* xl, unsigned short* Sh, unsigned short* Sl,
    const unsigned short* __restrict__ arena, int lay,
    const float* __restrict__ ln_s, const float* __restrict__ ln_b,
    const float* __restrict__ bq, const float* __restrict__ bk,
    const float* __restrict__ bv, unsigned short* __restrict__ qo,
    unsigned short* __restrict__ ko, unsigned short* __restrict__ voT,
    int tok0, int t) {
  int w = t >> 6, lane = t & 63;
  int lq = lane & 15, quad = lane >> 4;
  float ss = ln_s[lay * 64 + lane], sb = ln_b[lay * 64 + lane];
#pragma unroll
  for (int tk = 0; tk < 4; ++tk) {
    int tok = w * 4 + tk;
    float v = xl[tok * 64 + lane];
    float mean = wave_reduce_sum(v) * 0.015625f;
    float d = v - mean;
    float var = wave_reduce_sum(d * d) * 0.015625f;
    float hv = d * rsqrtf(var + 1e-6f) * ss + sb;
    unsigned short hi, lo;
    split_bf(hv, hi, lo);
    Sh[tok * 72 + lane] = hi;
    Sl[tok * 72 + lane] = lo;
  }
  __syncthreads();
  int b = tok0 >> 10, l0 = tok0 & 1023;
#pragma unroll 1
  for (int mat = 0; mat < 3; ++mat) {
    const unsigned short* Bh =
        arena + OFF_LAY0 + lay * LAY_STRIDE + mat * 16384;
    const unsigned short* Bl = Bh + 8192;
    const float* bias = (mat == 0 ? bq : mat == 1 ? bk : bv) + lay * 128;
#pragma unroll
    for (int j = 0; j < 2; ++j) {
      int tl = w + j * 4;  // head index
      int n = tl * 16 + lq;
      float bb = bias[n];
      floatx4 C = {bb, bb, bb, bb};
      C = mfma_tile<64, 72>(Sh, Sl, Bh + tl * 16 * 64, Bl + tl * 16 * 64,
                            lq, quad, C);
      if (mat < 2) {
        unsigned short* outp = (mat == 0 ? qo : ko);
        size_t basea = ((size_t)(b * 8 + tl) * 1024 + l0 + quad * 4) * 16 + lq;
#pragma unroll
        for (int r = 0; r < 4; ++r)
          outp[basea + (size_t)r * 16] = f2bf(C[r]);
      } else {
        size_t basev = ((size_t)(b * 8 + tl) * 16 + lq) * 1024 + l0 + quad * 4;
#pragma unroll
        for (int r = 0; r < 4; ++r)
          voT[basev + r] = f2bf(C[r]);
      }
    }
  }
}

// ---------------------------------------------------------------------------
// K1: input MLP + LN1 + QKV (layer 0). 16 tokens/block.
// ---------------------------------------------------------------------------
__global__ __launch_bounds__(256) void k_in_qkv(
    const float* __restrict__ embed, const float* __restrict__ z,
    const float* __restrict__ cond, const unsigned short* __restrict__ arena,
    const float* __restrict__ bin1, const float* __restrict__ bin2,
    float* __restrict__ x, const float* __restrict__ ln1_s,
    const float* __restrict__ ln1_b, const float* __restrict__ bq,
    const float* __restrict__ bk, const float* __restrict__ bv,
    unsigned short* __restrict__ qo, unsigned short* __restrict__ ko,
    unsigned short* __restrict__ voT) {
  __shared__ __align__(16) unsigned short Ah[16 * 136], Al[16 * 136];
  __shared__ __align__(16) unsigned short Hh[16 * 264], Hl[16 * 264];
  __shared__ __align__(16) unsigned short Sh[16 * 72], Sl[16 * 72];
  __shared__ float xl[16 * 64];
  int t = threadIdx.x, w = t >> 6, lane = t & 63;
  int lq = lane & 15, quad = lane >> 4;
  int tok0 = blockIdx.x * 16;
  for (int idx = t; idx < 2048; idx += 256) {
    int tok = idx >> 7, dim = idx & 127;
    int bl = tok0 + tok, l = bl & (LL - 1);
    float v;
    if (dim < 123) v = embed[l * 123 + dim];
    else if (dim == 123) v = z[bl];
    else v = cond[dim - 124];
    unsigned short hi, lo;
    split_bf(v, hi, lo);
    Ah[tok * 136 + dim] = hi;
    Al[tok * 136 + dim] = lo;
  }
  __syncthreads();
  // G1: 128 -> 256, gelu
  const unsigned short* B1h = arena + OFF_WIN1;
  const unsigned short* B1l = B1h + 32768;
#pragma unroll
  for (int j = 0; j < 4; ++j) {
    int tl = w * 4 + j, n = tl * 16 + lq;
    float bb = bin1[n];
    floatx4 C = {bb, bb, bb, bb};
    C = mfma_tile<128, 136>(Ah, Al, B1h + tl * 16 * 128, B1l + tl * 16 * 128,
                            lq, quad, C);
#pragma unroll
    for (int r = 0; r < 4; ++r) {
      float g = gelu_tanh(C[r]);
      unsigned short hi, lo;
      split_bf(g, hi, lo);
      Hh[(quad * 4 + r) * 264 + n] = hi;
      Hl[(quad * 4 + r) * 264 + n] = lo;
    }
  }
  __syncthreads();
  // G2: 256 -> 64 -> x (global + xl)
  const unsigned short* B2h = arena + OFF_WIN2;
  const unsigned short* B2l = B2h + 16384;
  {
    int n = w * 16 + lq;
    float bb = bin2[n];
    floatx4 C = {bb, bb, bb, bb};
    C = mfma_tile<256, 264>(Hh, Hl, B2h + w * 16 * 256, B2l + w * 16 * 256,
                            lq, quad, C);
#pragma unroll
    for (int r = 0; r < 4; ++r) {
      int m = quad * 4 + r;
      x[(size_t)(tok0 + m) * 64 + n] = C[r];
      xl[m * 64 + n] = C[r];
    }
  }
  __syncthreads();
  qkv_tail(xl, Sh, Sl, arena, 0, ln1_s, ln1_b, bq, bk, bv,
           qo, ko, voT, tok0, t);
}

// ---------------------------------------------------------------------------
// K4: MFMA flash attention, SPLIT-K over 2 halves (grid 2048; half=bid>>10).
// No-max exp2 softmax is LINEAR in keys, so halves combine by plain addition
// in the consumer (exactly 2 addends -> bit-deterministic). Each block does
// 8 chunks of 64 keys; writes UNNORMALIZED O and per-(tok,h) l.
// ---------------------------------------------------------------------------
__global__ __launch_bounds__(256) void k_attn(
    const unsigned short* __restrict__ qg, const unsigned short* __restrict__ kg,
    const unsigned short* __restrict__ vgT, const unsigned short* __restrict__ biasT,
    float* __restrict__ og, float* __restrict__ lsum) {
  __shared__ __align__(16) unsigned short Kl[64 * 32];     // 4 KB
  __shared__ __align__(16) unsigned short VT[16 * 72];     // 2.25 KB
  __shared__ __align__(16) unsigned short Pl[4][16 * 72];  // 9 KB
  __shared__ __align__(16) unsigned short Bch[64 * 72];    // 9 KB [q][k]
  int t = threadIdx.x, w = t >> 6, lane = t & 63;
  int lq = lane & 15, quad = lane >> 4;
  int bid = blockIdx.x;
  int half = bid >> 10;
  int rem = bid & 1023;
  int b = rem >> 7, h = (rem >> 4) & 7, qblk = rem & 15;
  int q0w = qblk * 64 + w * 16;
  int kbase = half * 512;
  size_t bh = (size_t)(b * 8 + h) * 1024;
  size_t bh16 = (size_t)(b * 8 + h) * 16;

  ((uint4*)Kl)[t] = uint4{0, 0, 0, 0};  // zero d16..31 pad

  short8 Qb = {};
  if (quad < 2)
    Qb = *(const short8*)(qg + (bh + q0w + lq) * 16 + quad * 8);

  float l = 0.0f;
  floatx4 O = {0.0f, 0.0f, 0.0f, 0.0f};

  // staging assignments (all vectorized), offset to this half's key range
  int key = t >> 2, dp = (t & 3) * 4;        // K: 1 uint2 / thread
  int drow = t >> 4, vcol = (t & 15) * 4;    // V^T: 1 uint2 / thread
  int qrow = t >> 2, bcol = (t & 3) * 16;    // bias: 2 uint4 / thread (16 ush)
  const unsigned short* kgp = kg + (bh + kbase + key) * 16 + dp;
  const unsigned short* vgp = vgT + (bh16 + drow) * 1024 + kbase + vcol;
  const unsigned short* bgp =
      biasT + ((size_t)(h * 1024 + qblk * 64 + qrow)) * 1024 + kbase + bcol;

  uint2 kpre = *(const uint2*)(kgp);
  uint2 vpre = *(const uint2*)(vgp);
  uint4 bpre0 = *(const uint4*)(bgp);
  uint4 bpre1 = *(const uint4*)(bgp + 8);

#pragma unroll 1
  for (int kc = 0; kc < 512; kc += 64) {
    __syncthreads();
    *(uint2*)(Kl + key * 32 + dp) = kpre;
    *(uint2*)(VT + drow * 72 + vcol) = vpre;
    *(uint4*)(Bch + qrow * 72 + bcol) = bpre0;
    *(uint4*)(Bch + qrow * 72 + bcol + 8) = bpre1;
    __syncthreads();
    if (kc + 64 < 512) {
      kpre = *(const uint2*)(kgp + (size_t)(kc + 64) * 16);
      vpre = *(const uint2*)(vgp + (kc + 64));
      bpre0 = *(const uint4*)(bgp + (kc + 64));
      bpre1 = *(const uint4*)(bgp + (kc + 64) + 8);
    }
    // QK^T + bias -> p = exp2(s) directly (offset is in the seed)
    float psum = 0.0f;
    unsigned short* pw = &Pl[w][lq * 72];
#pragma unroll
    for (int tile = 0; tile < 4; ++tile) {
      short8 A = *(const short8*)(Kl + (tile * 16 + lq) * 32 + quad * 8);
      floatx4 c = {QK_SEED, QK_SEED, QK_SEED, QK_SEED};
      c = __builtin_amdgcn_mfma_f32_16x16x32_bf16(A, Qb, c, 0, 0, 0);
      ushort4 bb = *(const ushort4*)(Bch + (w * 16 + lq) * 72 +
                                     tile * 16 + quad * 4);
      float p0 = exp2f(fmaf(c[0], 0.25f * LOG2E, bf2f(bb.x)));
      float p1 = exp2f(fmaf(c[1], 0.25f * LOG2E, bf2f(bb.y)));
      float p2 = exp2f(fmaf(c[2], 0.25f * LOG2E, bf2f(bb.z)));
      float p3 = exp2f(fmaf(c[3], 0.25f * LOG2E, bf2f(bb.w)));
      psum += (p0 + p1) + (p2 + p3);
      uint2 pk;
      pk.x = pack_bf2(p0, p1);
      pk.y = pack_bf2(p2, p3);
      *(uint2*)(pw + tile * 16 + quad * 4) = pk;
    }
    psum += __shfl_xor(psum, 16, 64);
    psum += __shfl_xor(psum, 32, 64);
    l += psum;
    asm volatile("s_waitcnt lgkmcnt(0)" ::: "memory");
    // PV: 2 MFMAs (K=32 keys each)
#pragma unroll
    for (int i = 0; i < 2; ++i) {
      short8 Pa = *(const short8*)(pw + i * 32 + quad * 8);
      short8 Vb = *(const short8*)(&VT[lq * 72 + i * 32 + quad * 8]);
      O = __builtin_amdgcn_mfma_f32_16x16x32_bf16(Pa, Vb, O, 0, 0, 0);
    }
  }
  // write unnormalized partial O (row=q=quad*4+r, col=d=lq) and l
  float* ogh = og + (size_t)half * OB_HALF;
#pragma unroll
  for (int r = 0; r < 4; ++r)
    ogh[((size_t)(b * 1024 + q0w + quad * 4 + r)) * 128 + h * 16 + lq] = O[r];
  if (quad == 0)
    lsum[(size_t)half * L_HALF + (size_t)(b * 1024 + q0w + lq) * 8 + h] = l;
}

// Shared proj+LN2+FFN body. Combines the two attn halves during staging.
__device__ __forceinline__ void pf_body(
    const float* __restrict__ ob, const float* __restrict__ lsum,
    const unsigned short* __restrict__ arena,
    const float* __restrict__ bo, float* __restrict__ x,
    const float* __restrict__ ln_s, const float* __restrict__ ln_b,
    const float* __restrict__ b1, const float* __restrict__ b2, int lay,
    unsigned short* Ah, unsigned short* Al, unsigned short* Sh,
    unsigned short* Sl, unsigned short* Hh, unsigned short* Hl, float* xl,
    int tok0, int t, bool write_x) {
  int w = t >> 6, lane = t & 63;
  int lq = lane & 15, quad = lane >> 4;
  const unsigned short* labase = arena + OFF_LAY0 + lay * LAY_STRIDE;
  const float* ob1 = ob + OB_HALF;
  // stage attn-o: combine halves, normalize, split
  for (int idx = t * 4; idx < 2048; idx += 1024) {
    int row = idx >> 7, col = idx & 127;
    int hh = col >> 4;
    int tok = tok0 + row;
    float lv = lsum[(size_t)tok * 8 + hh] +
               lsum[L_HALF + (size_t)tok * 8 + hh];
    float linv = 1.0f / lv;
    float4 v0 = *(const float4*)(ob + (size_t)tok * 128 + col);
    float4 v1 = *(const float4*)(ob1 + (size_t)tok * 128 + col);
    float4 v;
    v.x = (v0.x + v1.x) * linv;
    v.y = (v0.y + v1.y) * linv;
    v.z = (v0.z + v1.z) * linv;
    v.w = (v0.w + v1.w) * linv;
    unsigned short h0, e0, h1, e1, h2, e2, h3, e3;
    split_bf(v.x, h0, e0); split_bf(v.y, h1, e1);
    split_bf(v.z, h2, e2); split_bf(v.w, h3, e3);
    unsigned* ph = (unsigned*)(Ah + row * 136 + col);
    ph[0] = (unsigned)h0 | ((unsigned)h1 << 16);
    ph[1] = (unsigned)h2 | ((unsigned)h3 << 16);
    unsigned* pl = (unsigned*)(Al + row * 136 + col);
    pl[0] = (unsigned)e0 | ((unsigned)e1 << 16);
    pl[1] = (unsigned)e2 | ((unsigned)e3 << 16);
  }
  __syncthreads();
  // proj: 128 -> 64, + residual -> xl
  {
    const unsigned short* Bh = labase + OFF_WO;
    const unsigned short* Bl = Bh + 8192;
    int n = w * 16 + lq;
    float bb = bo[lay * 64 + n];
    floatx4 C = {bb, bb, bb, bb};
    C = mfma_tile<128, 136>(Ah, Al, Bh + w * 16 * 128, Bl + w * 16 * 128,
                            lq, quad, C);
#pragma unroll
    for (int r = 0; r < 4; ++r) {
      int m = quad * 4 + r;
      xl[m * 64 + n] = x[(size_t)(tok0 + m) * 64 + n] + C[r];
    }
  }
  __syncthreads();
  // LN2 -> Sh/Sl
  {
    float ss = ln_s[lay * 64 + lane], sb = ln_b[lay * 64 + lane];
#pragma unroll
    for (int tk = 0; tk < 4; ++tk) {
      int tok = w * 4 + tk;
      float v = xl[tok * 64 + lane];
      float mean = wave_reduce_sum(v) * 0.015625f;
      float d = v - mean;
      float var = wave_reduce_sum(d * d) * 0.015625f;
      float hv = d * rsqrtf(var + 1e-6f) * ss + sb;
      unsigned short hi, lo;
      split_bf(hv, hi, lo);
      Sh[tok * 72 + lane] = hi;
      Sl[tok * 72 + lane] = lo;
    }
  }
  __syncthreads();
  // FFN G1: 64 -> 256, gelu
  {
    const unsigned short* Bh = labase + OFF_W1;
    const unsigned short* Bl = Bh + 16384;
#pragma unroll
    for (int j = 0; j < 4; ++j) {
      int tl = w * 4 + j, n = tl * 16 + lq;
      float bb = b1[lay * 256 + n];
      floatx4 C = {bb, bb, bb, bb};
      C = mfma_tile<64, 72>(Sh, Sl, Bh + tl * 16 * 64, Bl + tl * 16 * 64,
                            lq, quad, C);
#pragma unroll
      for (int r = 0; r < 4; ++r) {
        float g = gelu_tanh(C[r]);
        unsigned short hi, lo;
        split_bf(g, hi, lo);
        Hh[(quad * 4 + r) * 264 + n] = hi;
        Hl[(quad * 4 + r) * 264 + n] = lo;
      }
    }
  }
  __syncthreads();
  // FFN G2: 256 -> 64, + residual -> xl (and optionally x)
  {
    const unsigned short* Bh = labase + OFF_W2;
    const unsigned short* Bl = Bh + 16384;
    int n = w * 16 + lq;
    float bb = b2[lay * 64 + n];
    floatx4 C = {bb, bb, bb, bb};
    C = mfma_tile<256, 264>(Hh, Hl, Bh + w * 16 * 256, Bl + w * 16 * 256,
                            lq, quad, C);
#pragma unroll
    for (int r = 0; r < 4; ++r) {
      int m = quad * 4 + r;
      float xv = xl[m * 64 + n] + C[r];
      xl[m * 64 + n] = xv;
      if (write_x) x[(size_t)(tok0 + m) * 64 + n] = xv;
    }
  }
  __syncthreads();
}

// ---------------------------------------------------------------------------
// K5a: proj+LN2+FFN (layer lay) then LN1+QKV (layer lay+1).
// ---------------------------------------------------------------------------
__global__ __launch_bounds__(256) void k_pf_qkv(
    const float* __restrict__ ob, const float* __restrict__ lsum,
    const unsigned short* __restrict__ arena,
    const float* __restrict__ bo, float* __restrict__ x,
    const float* __restrict__ ln2_s, const float* __restrict__ ln2_b,
    const float* __restrict__ b1, const float* __restrict__ b2, int lay,
    const float* __restrict__ ln1_s, const float* __restrict__ ln1_b,
    const float* __restrict__ bq, const float* __restrict__ bk,
    const float* __restrict__ bv, unsigned short* __restrict__ qo,
    unsigned short* __restrict__ ko, unsigned short* __restrict__ voT) {
  __shared__ __align__(16) unsigned short Ah[16 * 136], Al[16 * 136];
  __shared__ __align__(16) unsigned short Sh[16 * 72], Sl[16 * 72];
  __shared__ __align__(16) unsigned short Hh[16 * 264], Hl[16 * 264];
  __shared__ float xl[16 * 64];
  int t = threadIdx.x;
  int tok0 = blockIdx.x * 16;
  pf_body(ob, lsum, arena, bo, x, ln2_s, ln2_b, b1, b2, lay,
          Ah, Al, Sh, Sl, Hh, Hl, xl, tok0, t, true);
  qkv_tail(xl, Sh, Sl, arena, lay + 1, ln1_s, ln1_b, bq, bk, bv,
           qo, ko, voT, tok0, t);
}

// ---------------------------------------------------------------------------
// K5b: proj+LN2+FFN (last layer) then head MLP.
// ---------------------------------------------------------------------------
__global__ __launch_bounds__(256) void k_pf_head(
    const float* __restrict__ ob, const float* __restrict__ lsum,
    const unsigned short* __restrict__ arena,
    const float* __restrict__ bo, float* __restrict__ x,
    const float* __restrict__ ln2_s, const float* __restrict__ ln2_b,
    const float* __restrict__ b1, const float* __restrict__ b2, int lay,
    const float* __restrict__ bh1, const float* __restrict__ bh2,
    const float* __restrict__ Wh3, const float* __restrict__ bh3,
    float* __restrict__ out) {
  __shared__ __align__(16) unsigned short Ah[16 * 136], Al[16 * 136];
  __shared__ __align__(16) unsigned short Sh[16 * 72], Sl[16 * 72];
  __shared__ __align__(16) unsigned short Hh[16 * 264], Hl[16 * 264];
  __shared__ float xl[16 * 64];
  int t = threadIdx.x, w = t >> 6, lane = t & 63;
  int lq = lane & 15, quad = lane >> 4;
  int tok0 = blockIdx.x * 16;
  pf_body(ob, lsum, arena, bo, x, ln2_s, ln2_b, b1, b2, lay,
          Ah, Al, Sh, Sl, Hh, Hl, xl, tok0, t, false);
  // split raw x -> Sh/Sl
#pragma unroll
  for (int tk = 0; tk < 4; ++tk) {
    int tok = w * 4 + tk;
    unsigned short hi, lo;
    split_bf(xl[tok * 64 + lane], hi, lo);
    Sh[tok * 72 + lane] = hi;
    Sl[tok * 72 + lane] = lo;
  }
  __syncthreads();
  // head G1: 64 -> 256, gelu
  {
    const unsigned short* Bh = arena + OFF_WH1;
    const unsigned short* Bl = Bh + 16384;
#pragma unroll
    for (int j = 0; j < 4; ++j) {
      int tl = w * 4 + j, n = tl * 16 + lq;
      float bb = bh1[n];
      floatx4 C = {bb, bb, bb, bb};
      C = mfma_tile<64, 72>(Sh, Sl, Bh + tl * 16 * 64, Bl + tl * 16 * 64,
                            lq, quad, C);
#pragma unroll
      for (int r = 0; r < 4; ++r) {
        float g = gelu_tanh(C[r]);
        unsigned short hi, lo;
        split_bf(g, hi, lo);
        Hh[(quad * 4 + r) * 264 + n] = hi;
        Hl[(quad * 4 + r) * 264 + n] = lo;
      }
    }
  }
  __syncthreads();
  // head G2: 256 -> 64, gelu -> xl (reused as h2s)
  {
    const unsigned short* Bh = arena + OFF_WH2;
    const unsigned short* Bl = Bh + 16384;
    int n = w * 16 + lq;
    float bb = bh2[n];
    floatx4 C = {bb, bb, bb, bb};
    C = mfma_tile<256, 264>(Hh, Hl, Bh + w * 16 * 256, Bl + w * 16 * 256,
                            lq, quad, C);
    __syncthreads();
#pragma unroll
    for (int r = 0; r < 4; ++r)
      xl[(quad * 4 + r) * 64 + n] = gelu_tanh(C[r]);
  }
  __syncthreads();
  // head G3: dot with Wh3
  float wv3 = Wh3[lane];
#pragma unroll
  for (int tk = 0; tk < 4; ++tk) {
    int tok = w * 4 + tk;
    float v = xl[tok * 64 + lane] * wv3;
    float sum = wave_reduce_sum(v);
    if (lane == 0) out[tok0 + tok] = sum + bh3[0];
  }
}

// ---------------------------------------------------------------------------
extern "C" void kernel_launch(void* const* d_in, const int* in_sizes, int n_in,
                              void* d_out, int out_size, void* d_ws, size_t ws_size,
                              hipStream_t stream) {
  const float* z      = (const float*)d_in[0];
  const float* cond   = (const float*)d_in[1];
  const float* s      = (const float*)d_in[2];
  const float* embed  = (const float*)d_in[3];
  const float* Win1   = (const float*)d_in[4];
  const float* bin1   = (const float*)d_in[5];
  const float* Win2   = (const float*)d_in[6];
  const float* bin2   = (const float*)d_in[7];
  const float* ln1_s  = (const float*)d_in[8];
  const float* ln1_b  = (const float*)d_in[9];
  const float* ln2_s  = (const float*)d_in[10];
  const float* ln2_b  = (const float*)d_in[11];
  const float* Wq     = (const float*)d_in[12];
  const float* bq     = (const float*)d_in[13];
  const float* Wk     = (const float*)d_in[14];
  const float* bk     = (const float*)d_in[15];
  const float* Wv     = (const float*)d_in[16];
  const float* bv     = (const float*)d_in[17];
  const float* Wo     = (const float*)d_in[18];
  const float* bo     = (const float*)d_in[19];
  const float* rbf_c  = (const float*)d_in[20];
  const float* rbf_lw = (const float*)d_in[21];
  const float* rbf_w  = (const float*)d_in[22];
  const float* rbf_b  = (const float*)d_in[23];
  const float* W1     = (const float*)d_in[24];
  const float* b1     = (const float*)d_in[25];
  const float* W2     = (const float*)d_in[26];
  const float* b2     = (const float*)d_in[27];
  const float* Wh1    = (const float*)d_in[28];
  const float* bh1    = (const float*)d_in[29];
  const float* Wh2    = (const float*)d_in[30];
  const float* bh2    = (const float*)d_in[31];
  const float* Wh3    = (const float*)d_in[32];
  const float* bh3    = (const float*)d_in[33];

  char* base = (char*)d_ws;
  float*          x     = (float*)(base);                          // 2 MB
  unsigned short* qb    = (unsigned short*)(base + (2u << 20));    // 2 MB
  unsigned short* kb    = (unsigned short*)(base + (4u << 20));    // 2 MB
  unsigned short* vbT   = (unsigned short*)(base + (6u << 20));    // 2 MB
  float*          ob    = (float*)(base + (8u << 20));             // 2 x 4 MB
  float*          lsum  = (float*)(base + (16u << 20));            // 512 KB
  unsigned short* biasT = (unsigned short*)(base + (17u << 20));   // 2 x 16 MB
  unsigned short* arena = (unsigned short*)(base + (50u << 20));   // ~832 KB

  PrepArgs pa;
  auto set = [&](int i, const float* sp, int K, int N, int dst) {
    pa.src[i] = sp; pa.Kd[i] = K; pa.Nd[i] = N; pa.dst[i] = dst;
    pa.elems[i] = K * N;
  };
  set(0, Win1, 128, 256, OFF_WIN1);
  set(1, Win2, 256, 64, OFF_WIN2);
  for (int lay = 0; lay < 2; ++lay) {
    int lb = OFF_LAY0 + lay * LAY_STRIDE;
    set(2 + lay * 6, Wq + lay * 8192, 64, 128, lb + OFF_WQ);
    set(3 + lay * 6, Wk + lay * 8192, 64, 128, lb + OFF_WK);
    set(4 + lay * 6, Wv + lay * 8192, 64, 128, lb + OFF_WV);
    set(5 + lay * 6, Wo + lay * 8192, 128, 64, lb + OFF_WO);
    set(6 + lay * 6, W1 + lay * 16384, 64, 256, lb + OFF_W1);
    set(7 + lay * 6, W2 + lay * 16384, 256, 64, lb + OFF_W2);
  }
  set(14, Wh1, 64, 256, OFF_WH1);
  set(15, Wh2, 256, 64, OFF_WH2);

  k_prep_bias<<<2048 + 8192, 256, 0, stream>>>(pa, arena, s, rbf_c, rbf_lw,
                                               rbf_w, rbf_b, biasT);
  k_in_qkv<<<512, 256, 0, stream>>>(embed, z, cond, arena, bin1, bin2, x,
                                    ln1_s, ln1_b, bq, bk, bv, qb, kb, vbT);
  k_attn<<<2048, 256, 0, stream>>>(qb, kb, vbT, biasT, ob, lsum);
  k_pf_qkv<<<512, 256, 0, stream>>>(ob, lsum, arena, bo, x, ln2_s, ln2_b,
                                    b1, b2, 0, ln1_s, ln1_b, bq, bk, bv,
                                    qb, kb, vbT);
  k_attn<<<2048, 256, 0, stream>>>(qb, kb, vbT,
                                   biasT + (size_t)8 * 1024 * 1024, ob, lsum);
  k_pf_head<<<512, 256, 0, stream>>>(ob, lsum, arena, bo, x, ln2_s, ln2_b,
                                     b1, b2, 1, bh1, bh2, Wh3, bh3,
                                     (float*)d_out);
}